// Round 4
// baseline (333.701 us; speedup 1.0000x reference)
//
#include <hip/hip_runtime.h>
#include <cmath>

// ---------------------------------------------------------------- types
typedef __bf16 bf16x8 __attribute__((ext_vector_type(8)));
typedef __bf16 bf16x4 __attribute__((ext_vector_type(4)));
typedef float  floatx4 __attribute__((ext_vector_type(4)));

#define LN_EPS 1e-5f
#define INV_TEMP 0.125f   // 1/sqrt(64)

// B=32 S=512 D=512 H=8 DK=DV=64 DFF=2048, M = B*S = 16384
static const int Mrows = 16384;

__device__ __forceinline__ void gload_lds16(const void* g, void* l) {
  __builtin_amdgcn_global_load_lds(
      (const __attribute__((address_space(1))) void*)g,
      (__attribute__((address_space(3))) void*)l, 16, 0, 0);
}

// ---------------------------------------------------------------- fused prep: x->bf16 + 6 weight transposes
__global__ __launch_bounds__(256) void prep_kernel(const float* __restrict__ x, __bf16* __restrict__ xb,
                                                   const float* __restrict__ wq, const float* __restrict__ wk,
                                                   const float* __restrict__ wv, const float* __restrict__ wo,
                                                   const float* __restrict__ wff1, const float* __restrict__ wff2,
                                                   __bf16* __restrict__ tq, __bf16* __restrict__ tk,
                                                   __bf16* __restrict__ tv, __bf16* __restrict__ to_,
                                                   __bf16* __restrict__ tff1, __bf16* __restrict__ tff2) {
  const int bid = blockIdx.x, tid = threadIdx.x;
  if (bid < 8192) {
    int i = bid * 256 + tid;
    float4 v = ((const float4*)x)[i];
    __bf16* d = xb + i * 4;
    d[0] = (__bf16)v.x; d[1] = (__bf16)v.y; d[2] = (__bf16)v.z; d[3] = (__bf16)v.w;
    return;
  }
  __shared__ __bf16 til[64][72];
  int t = bid - 8192;
  const float* src; __bf16* dst; int R, C, bx, by;
  if (t < 256) {
    int w = t >> 6, tt = t & 63;
    const float* srcs[4] = {wq, wk, wv, wo};
    __bf16* dsts[4] = {tq, tk, tv, to_};
    src = srcs[w]; dst = dsts[w]; R = 512; C = 512; bx = tt & 7; by = tt >> 3;
  } else if (t < 512) {
    int tt = t - 256;
    src = wff1; dst = tff1; R = 512; C = 2048; bx = tt & 31; by = tt >> 5;
  } else {
    int tt = t - 512;
    src = wff2; dst = tff2; R = 2048; C = 512; bx = tt & 7; by = tt >> 3;
  }
  const float* s = src + (size_t)(by * 64) * C + bx * 64;
  int r = tid >> 4, c4 = (tid & 15) * 4;
  for (int p = 0; p < 4; ++p) {
    int rr = r + p * 16;
    float4 v = *(const float4*)(s + (size_t)rr * C + c4);
    til[c4 + 0][rr] = (__bf16)v.x;
    til[c4 + 1][rr] = (__bf16)v.y;
    til[c4 + 2][rr] = (__bf16)v.z;
    til[c4 + 3][rr] = (__bf16)v.w;
  }
  __syncthreads();
  __bf16* d = dst + (size_t)(bx * 64) * R + by * 64;
  int orow = tid >> 3, oc8 = (tid & 7) * 8;
  for (int p = 0; p < 2; ++p) {
    int rr = orow + p * 32;
    *(bf16x8*)(d + (size_t)rr * R + oc8) = *(const bf16x8*)(&til[rr][oc8]);
  }
}

// ---------------------------------------------------------------- 256^2 8-wave GEMM, 4-slot K-half ring
// Tile 256x256, 512 threads (waves 2Mx4N). LDS = 4 slots x 32KB, each slot one
// K-half (K=32): A[256x32] (16KB) + B[256x32] (16KB), pair-interleaved lines:
//   line p (=row>>1, 128B) holds rows {2p,2p+1}; 16B slot sl holds logical
//   (kseg=slog>>1, w=slog&1) with slog = sl ^ (p&7)   [<=2-way bank conflict]
// Phase h: vmcnt(8) -> barrier -> 12 ds_read_b128 (A 8, B 4) -> stage half h+3
//   (4 gload_lds16/thread) -> 32 MFMA (setprio). Loads have 3 phases (~960cy)
//   to land >= HBM latency; vmcnt never drains in main loop (tail 8->4->0).
// EPI: 0 plain bf16, 2 bias+relu, 4 QKV (inverse q/k norms + V-transpose).
// NKS>1 = split-K, slice ks writes Cv + ks*M*NDIM.
template <int EPI, int NBN, int NDIM, int KDIM, int NKS>
__global__ __launch_bounds__(512, 2) void gemm256(const __bf16* __restrict__ A,
                                                  const __bf16* __restrict__ Bt,
                                                  __bf16* __restrict__ Cv,
                                                  const float* __restrict__ bias,
                                                  float* __restrict__ norms,
                                                  __bf16* __restrict__ vtg) {
  __shared__ __align__(16) char smem[131072];
  const int tid = threadIdx.x;
  const int wave = tid >> 6, lane = tid & 63;
  const int l15 = lane & 15, quad = lane >> 4;
  const int wm = wave >> 2, wn = wave & 3;

  constexpr int NBM = Mrows / 256;          // 64
  constexpr int NBLK = NBM * NBN * NKS;     // divisible by 8 for all instantiations
  constexpr int KS = KDIM / NKS;
  constexpr int NTH = KS / 32;              // K-half count (>= 8 everywhere)

  int id = blockIdx.x;
  int t = (id & 7) * (NBLK >> 3) + (id >> 3);   // XCD-chunked bijective swizzle
  const int ks = t / (NBM * NBN);
  t -= ks * (NBM * NBN);
  const int nblk = t % NBN, mblk = t / NBN;
  const int m0 = mblk * 256, n0 = nblk * 256;
  const __bf16* Ab = A + (size_t)ks * KS;
  const __bf16* Bb = Bt + (size_t)ks * KS;
  __bf16* Cw = Cv + (size_t)ks * Mrows * NDIM;
  (void)bias;

  // ---- stage mapping: waves 0-3 stage A (rows wq*64+[0,64)), waves 4-7 B.
  // batch bi = wq*4+j covers rows bi*16..+16 of its matrix for one K-half.
  // lane l: line-in-batch l>>3, phys 16B-slot l&7 -> logical slog=(l&7)^(l>>3)
  const int wq = wave & 3, isB = wave >> 2;
  const int l3 = lane >> 3, sl7 = lane & 7;
  const int slog = sl7 ^ l3;
  const int wbit = slog & 1, kseg = slog >> 1;
  const int rl = l3 * 2 + wbit;
  const __bf16* sbase = (isB ? Bb + (size_t)(n0 + wq * 64 + rl) * KDIM
                             : Ab + (size_t)(m0 + wq * 64 + rl) * KDIM) + kseg * 8;
  const int ldob = isB * 16384 + wq * 4096 + lane * 16;

  // ---- fragment read offsets (byte): A frag i -> row wm*128+i*16+l15, k=quad*8
  const int rsw = (l15 >> 1) * 128 + ((((quad << 1) | (l15 & 1)) ^ (l15 >> 1)) * 16);
  const int wmBase = wm * 8192;
  const int wnBase = wn * 4096;

  floatx4 zero = {0.f, 0.f, 0.f, 0.f};
  floatx4 acc[8][4];
#pragma unroll
  for (int i = 0; i < 8; ++i)
#pragma unroll
    for (int j = 0; j < 4; ++j) acc[i][j] = zero;

#define STAGEH(h)                                                            \
  {                                                                          \
    _Pragma("unroll") for (int j = 0; j < 4; ++j)                            \
        gload_lds16(sbase + (size_t)j * (16 * KDIM) + (h) * 32,              \
                    smem + ((h) & 3) * 32768 + ldob + j * 1024);             \
  }

#define PHASE(h, DOSTAGE, VM)                                                \
  {                                                                          \
    asm volatile("s_waitcnt vmcnt(" #VM ")" ::: "memory");                   \
    __builtin_amdgcn_s_barrier();                                            \
    const char* slotp = smem + ((h) & 3) * 32768;                            \
    bf16x8 aF[8], bF[4];                                                     \
    _Pragma("unroll") for (int i = 0; i < 8; ++i)                            \
      aF[i] = *(const bf16x8*)(slotp + wmBase + i * 1024 + rsw);             \
    _Pragma("unroll") for (int j = 0; j < 4; ++j)                            \
      bF[j] = *(const bf16x8*)(slotp + 16384 + wnBase + j * 1024 + rsw);     \
    if (DOSTAGE) STAGEH((h) + 3);                                            \
    __builtin_amdgcn_s_setprio(1);                                           \
    _Pragma("unroll") for (int i = 0; i < 8; ++i)                            \
      _Pragma("unroll") for (int j = 0; j < 4; ++j)                          \
        acc[i][j] = __builtin_amdgcn_mfma_f32_16x16x32_bf16(aF[i], bF[j],    \
                                                            acc[i][j], 0, 0, 0); \
    __builtin_amdgcn_s_setprio(0);                                           \
  }

  // prologue: stage halves 0,1,2 into slots 0,1,2 (loop's vmcnt(8) covers h=0)
  STAGEH(0); STAGEH(1); STAGEH(2);

  for (int h = 0; h <= NTH - 4; ++h) PHASE(h, 1, 8);
  PHASE(NTH - 3, 0, 8);
  PHASE(NTH - 2, 0, 4);
  PHASE(NTH - 1, 0, 0);

#undef STAGEH
#undef PHASE

  if (EPI == 4) {
    int head_global = (n0 + wn * 64) >> 6;
    int kind = head_global >> 3;          // block-uniform: 0=q 1=k 2=v
    if (kind < 2) {
      // fused INVERSE q/k norms; then fall through to the normal C write
      int h = head_global & 7;
#pragma unroll
      for (int ii = 0; ii < 8; ++ii)
#pragma unroll
        for (int r = 0; r < 4; ++r) {
          float sq = 0.f;
#pragma unroll
          for (int jj = 0; jj < 4; ++jj) {
            float v = acc[ii][jj][r];
            sq += v * v;
          }
          for (int m = 1; m < 16; m <<= 1) sq += __shfl_xor(sq, m, 64);
          if (l15 == 0) {
            int arow = m0 + wm * 128 + ii * 16 + quad * 4 + r;
            int bb = arow >> 9, ss = arow & 511;
            norms[kind * 131072 + ((bb << 3) + h) * 512 + ss] = rsqrtf(sq);
          }
        }
    } else {
      // V blocks: transpose through LDS straight into vtg[bh][d][s]
      const int PADT = 136;
      __bf16* Ct = (__bf16*)smem;     // [256 cols][128 rows-of-half + pad]
      int bb = m0 >> 9, s0r = m0 & 511;
#pragma unroll
      for (int hh = 0; hh < 2; ++hh) {
        __builtin_amdgcn_s_barrier();
        if (wm == hh) {
#pragma unroll
          for (int ii = 0; ii < 8; ++ii)
#pragma unroll
            for (int jj = 0; jj < 4; ++jj) {
              bf16x4 pk;
#pragma unroll
              for (int r = 0; r < 4; ++r) pk[r] = (__bf16)acc[ii][jj][r];
              *(bf16x4*)(Ct + (wn * 64 + jj * 16 + l15) * PADT + ii * 16 + quad * 4) = pk;
            }
        }
        __builtin_amdgcn_s_barrier();
#pragma unroll
        for (int p = 0; p < 8; ++p) {
          int c = p * 32 + (tid >> 4);        // local col 0..255 (d within 4 heads)
          int s8 = (tid & 15) * 8;            // s-offset within half
          int h = ((n0 + c) >> 6) & 7, d = c & 63;
          *(bf16x8*)(vtg + ((size_t)(((bb << 3) + h) * 64 + d)) * 512 + s0r + hh * 128 + s8) =
              *(const bf16x8*)(Ct + c * PADT + s8);
        }
      }
      return;
    }
  }

  // normal epilogue: per 128-row half through LDS, wide stores
  const int PADC = 264;
  __bf16* Cs = (__bf16*)smem;
  float bv[4];
  if (EPI == 2) {
#pragma unroll
    for (int j = 0; j < 4; ++j) bv[j] = bias[n0 + wn * 64 + j * 16 + l15];
  }
#pragma unroll
  for (int hh = 0; hh < 2; ++hh) {
    __builtin_amdgcn_s_barrier();
    if (wm == hh) {
#pragma unroll
      for (int i = 0; i < 8; ++i)
#pragma unroll
        for (int j = 0; j < 4; ++j)
#pragma unroll
          for (int r = 0; r < 4; ++r) {
            float v = acc[i][j][r];
            if (EPI == 2) {
              v += bv[j];
              v = v > 0.f ? v : 0.f;
            }
            Cs[(i * 16 + quad * 4 + r) * PADC + wn * 64 + j * 16 + l15] = (__bf16)v;
          }
    }
    __builtin_amdgcn_s_barrier();
#pragma unroll
    for (int p = 0; p < 8; ++p) {
      int rowl = p * 16 + (tid >> 5);
      int c8 = (tid & 31) * 8;
      *(bf16x8*)(Cw + (size_t)(m0 + hh * 128 + rowl) * NDIM + n0 + c8) =
          *(const bf16x8*)(Cs + rowl * PADC + c8);
    }
  }
}

// ---------------------------------------------------------------- attention
__global__ __launch_bounds__(256) void attn_kernel(const __bf16* __restrict__ qkv,
                                                   const __bf16* __restrict__ vtg,
                                                   const float* __restrict__ norms,
                                                   __bf16* __restrict__ out) {
  __shared__ __align__(16) __bf16 Ks[64 * 64];   // [sk][d]
  __shared__ __align__(16) __bf16 Vs[64 * 64];   // [d][sk]
  __shared__ __align__(16) __bf16 P2[4][16 * 72];
  const int tid = threadIdx.x, wave = tid >> 6, lane = tid & 63;
  const int l15 = lane & 15, quad = lane >> 4;
  const int bh = blockIdx.x & 255;
  const int qq = blockIdx.x >> 8;
  const int b = bh >> 3, h = bh & 7;
  const int qbase = qq * 128 + wave * 32;
  const int rs = lane >> 3;
  const int swz_st = ((lane & 7) ^ rs) * 8;
  const int s7 = l15 & 7;

  const __bf16* Qb = qkv + (size_t)(b * 512) * 1536 + h * 64;
  const __bf16* Kb = Qb + 512;
  const __bf16* Vtb = vtg + (size_t)bh * 32768;
  const float* nkinv = norms + 131072 + bh * 512;
  const float* nqinv = norms + bh * 512;
  __bf16* Pw = P2[wave];

  bf16x8 aq[2][2];
  float cq[2];
  for (int ch = 0; ch < 2; ++ch) {
    int qrow = qbase + ch * 16;
    aq[ch][0] = *(const bf16x8*)(Qb + (size_t)(qrow + l15) * 1536 + quad * 8);
    aq[ch][1] = *(const bf16x8*)(Qb + (size_t)(qrow + l15) * 1536 + 32 + quad * 8);
    cq[ch] = nqinv[qrow + l15] * INV_TEMP;
  }

  floatx4 zero = {0.f, 0.f, 0.f, 0.f};
  floatx4 o[2][4];
  float lsum[2] = {0.f, 0.f};
  for (int ch = 0; ch < 2; ++ch)
    for (int jd = 0; jd < 4; ++jd) o[ch][jd] = zero;

  for (int kt = 0; kt < 8; ++kt) {
    int s0 = kt * 64;
    __syncthreads();
    for (int c = 0; c < 4; ++c) {
      int g = wave * 4 + c;
      const __bf16* src;
      __bf16* dst;
      if (g < 8) {
        int sk = g * 8 + rs;
        src = Kb + (size_t)(s0 + sk) * 1536 + swz_st;
        dst = Ks + g * 512;
      } else {
        int g2 = g - 8;
        int d = g2 * 8 + rs;
        src = Vtb + (size_t)d * 512 + s0 + swz_st;
        dst = Vs + g2 * 512;
      }
      gload_lds16(src, dst + lane * 8);
    }
    __syncthreads();

    for (int ch = 0; ch < 2; ++ch) {
      // S^T: 64 sk x 16 q ; lane -> (sk = j*16+quad*4+r, q = l15)
      floatx4 z[4];
      for (int j = 0; j < 4; ++j) {
        int r64 = (j * 16 + l15) * 64;
        bf16x8 k0 = *(const bf16x8*)(Ks + r64 + ((quad ^ s7) * 8));
        bf16x8 k1 = *(const bf16x8*)(Ks + r64 + (((4 + quad) ^ s7) * 8));
        floatx4 zz = zero;
        zz = __builtin_amdgcn_mfma_f32_16x16x32_bf16(k0, aq[ch][0], zz, 0, 0, 0);
        zz = __builtin_amdgcn_mfma_f32_16x16x32_bf16(k1, aq[ch][1], zz, 0, 0, 0);
        z[j] = zz;
      }
      for (int j = 0; j < 4; ++j) {
        floatx4 nk4 = *(const floatx4*)(nkinv + s0 + j * 16 + quad * 4);
        bf16x4 pk;
        for (int r = 0; r < 4; ++r) {
          float p = __expf(z[j][r] * cq[ch] * nk4[r]);
          lsum[ch] += p;
          pk[r] = (__bf16)p;
        }
        *(bf16x4*)(Pw + l15 * 72 + j * 16 + quad * 4) = pk;
      }
      bf16x8 ap0 = *(const bf16x8*)(Pw + l15 * 72 + quad * 8);
      bf16x8 ap1 = *(const bf16x8*)(Pw + l15 * 72 + 32 + quad * 8);
      for (int jd = 0; jd < 4; ++jd) {
        int r64 = (jd * 16 + l15) * 64;
        bf16x8 v0 = *(const bf16x8*)(Vs + r64 + ((quad ^ s7) * 8));
        bf16x8 v1 = *(const bf16x8*)(Vs + r64 + (((4 + quad) ^ s7) * 8));
        o[ch][jd] = __builtin_amdgcn_mfma_f32_16x16x32_bf16(v0, ap0, o[ch][jd], 0, 0, 0);
        o[ch][jd] = __builtin_amdgcn_mfma_f32_16x16x32_bf16(v1, ap1, o[ch][jd], 0, 0, 0);
      }
    }
  }

  for (int ch = 0; ch < 2; ++ch) {
    float s = lsum[ch];
    s += __shfl_xor(s, 16, 64);
    s += __shfl_xor(s, 32, 64);
    float inv = __builtin_amdgcn_rcpf(s);
    int q = qbase + ch * 16 + l15;
    __bf16* op = out + (size_t)(b * 512 + q) * 512 + h * 64;
    for (int jd = 0; jd < 4; ++jd) {
      bf16x4 pk;
      for (int r = 0; r < 4; ++r) pk[r] = (__bf16)(o[ch][jd][r] * inv);
      *(bf16x4*)(op + jd * 16 + quad * 4) = pk;
    }
  }
}

// ---------------------------------------------------------------- residual + layernorm
template <bool X1BF, bool WF, bool WB, bool DUAL>
__global__ __launch_bounds__(256) void resid_ln(const float* __restrict__ X1f,
                                                const __bf16* __restrict__ X1b,
                                                const __bf16* __restrict__ X2,
                                                const __bf16* __restrict__ X2b,
                                                const float* __restrict__ bias,
                                                const float* __restrict__ g,
                                                const float* __restrict__ be,
                                                float* __restrict__ outf,
                                                __bf16* __restrict__ outb) {
  int row = blockIdx.x * 4 + (threadIdx.x >> 6);
  int lane = threadIdx.x & 63;
  float v[8];
  bf16x8 b8 = *(const bf16x8*)(X2 + (size_t)row * 512 + lane * 8);
  if (X1BF) {
    bf16x8 a = *(const bf16x8*)(X1b + (size_t)row * 512 + lane * 8);
    for (int i = 0; i < 8; ++i) v[i] = (float)a[i] + (float)b8[i];
  } else {
    const float4* r1 = (const float4*)(X1f + (size_t)row * 512);
    float4 a0 = r1[lane * 2], a1 = r1[lane * 2 + 1];
    v[0] = a0.x; v[1] = a0.y; v[2] = a0.z; v[3] = a0.w;
    v[4] = a1.x; v[5] = a1.y; v[6] = a1.z; v[7] = a1.w;
    for (int i = 0; i < 8; ++i) v[i] += (float)b8[i];
  }
  if (DUAL) {
    bf16x8 c8 = *(const bf16x8*)(X2b + (size_t)row * 512 + lane * 8);
    for (int i = 0; i < 8; ++i) v[i] += (float)c8[i];
  }
  if (bias) {
    const float* bp = bias + lane * 8;
    for (int i = 0; i < 8; ++i) v[i] += bp[i];
  }
  float s = 0.f, sq = 0.f;
  for (int i = 0; i < 8; ++i) {
    s += v[i];
    sq += v[i] * v[i];
  }
  for (int m = 1; m < 64; m <<= 1) {
    s += __shfl_xor(s, m, 64);
    sq += __shfl_xor(sq, m, 64);
  }
  float mean = s * (1.f / 512.f);
  float var = sq * (1.f / 512.f) - mean * mean;
  float rstd = rsqrtf(var + LN_EPS);
  const float* gp = g + lane * 8;
  const float* bp2 = be + lane * 8;
  float o[8];
  for (int i = 0; i < 8; ++i) o[i] = (v[i] - mean) * rstd * gp[i] + bp2[i];
  if (WF) {
    float4 w0 = {o[0], o[1], o[2], o[3]}, w1 = {o[4], o[5], o[6], o[7]};
    ((float4*)(outf + (size_t)row * 512))[lane * 2] = w0;
    ((float4*)(outf + (size_t)row * 512))[lane * 2 + 1] = w1;
  }
  if (WB) {
    __bf16 tmp[8];
    for (int i = 0; i < 8; ++i) tmp[i] = (__bf16)o[i];
    *(bf16x8*)(outb + (size_t)row * 512 + lane * 8) = *(bf16x8*)tmp;
  }
}

// ---------------------------------------------------------------- launcher
extern "C" void kernel_launch(void* const* d_in, const int* in_sizes, int n_in,
                              void* d_out, int out_size, void* d_ws, size_t ws_size,
                              hipStream_t stream) {
  const float* x     = (const float*)d_in[0];
  const float* w_q   = (const float*)d_in[1];
  const float* w_k   = (const float*)d_in[2];
  const float* w_v   = (const float*)d_in[3];
  const float* w_o   = (const float*)d_in[4];
  const float* w_ff1 = (const float*)d_in[5];
  const float* b_ff1 = (const float*)d_in[6];
  const float* w_ff2 = (const float*)d_in[7];
  const float* b_ff2 = (const float*)d_in[8];
  const float* g1    = (const float*)d_in[9];
  const float* b1    = (const float*)d_in[10];
  const float* g2    = (const float*)d_in[11];
  const float* b2    = (const float*)d_in[12];
  float* out = (float*)d_out;

  char* ws = (char*)d_ws;
  size_t off = 0;
  auto alloc = [&](size_t bytes) -> void* {
    void* p = ws + off;
    off += (bytes + 255) & ~(size_t)255;
    return p;
  };
  __bf16* xb     = (__bf16*)alloc((size_t)Mrows * 512 * 2);
  __bf16* wt_qkv = (__bf16*)alloc((size_t)1536 * 512 * 2);
  __bf16* wt_o   = (__bf16*)alloc((size_t)512 * 512 * 2);
  __bf16* wt_ff1 = (__bf16*)alloc((size_t)2048 * 512 * 2);
  __bf16* wt_ff2 = (__bf16*)alloc((size_t)512 * 2048 * 2);
  __bf16* qkv    = (__bf16*)alloc((size_t)Mrows * 1536 * 2);
  float*  norms  = (float*)alloc((size_t)262144 * 4);
  __bf16* attn   = (__bf16*)alloc((size_t)Mrows * 512 * 2);
  __bf16* projb  = (__bf16*)alloc((size_t)Mrows * 512 * 2);   // contiguous after attn
  __bf16* h1b    = (__bf16*)alloc((size_t)Mrows * 512 * 2);
  __bf16* mid    = (__bf16*)alloc((size_t)Mrows * 2048 * 2);
  __bf16* vtg    = mid;            // alias: vtg dead before w_o writes mid
  __bf16* wo_p   = mid;            // w_o split-K partials: mid + {0, M*512}
  __bf16* f2o    = attn;           // alias: attn dead after w_o GEMM; slice1 -> projb (dead)

  prep_kernel<<<8960, 256, 0, stream>>>(x, xb, w_q, w_k, w_v, w_o, w_ff1, w_ff2,
                                        wt_qkv, wt_qkv + 512 * 512, wt_qkv + 2 * 512 * 512,
                                        wt_o, wt_ff1, wt_ff2);

  // QKV (fused inverse norms + V-transpose into vtg), grid 64x6=384
  gemm256<4, 6, 1536, 512, 1><<<dim3(384), 512, 0, stream>>>(xb, wt_qkv, qkv, nullptr,
                                                             norms, vtg);
  attn_kernel<<<dim3(1024), 256, 0, stream>>>(qkv, vtg, norms, attn);
  // w_o proj -> two bf16 split-K partials into mid (grid 64x2x2=256)
  gemm256<0, 2, 512, 512, 2><<<dim3(256), 512, 0, stream>>>(attn, wt_o, wo_p, nullptr,
                                                            nullptr, nullptr);
  // LN1: x + wo_a + wo_b -> h1b (bf16)
  resid_ln<false, false, true, true><<<4096, 256, 0, stream>>>(x, nullptr, wo_p,
                                                               wo_p + (size_t)Mrows * 512,
                                                               nullptr, g1, b1, nullptr, h1b);
  // FFN1 (+bias, relu): grid 64x8=512
  gemm256<2, 8, 2048, 512, 1><<<dim3(512), 512, 0, stream>>>(h1b, wt_ff1, mid, b_ff1,
                                                             nullptr, nullptr);
  // FFN2 -> two bf16 split-K partials (grid 64x2x2=256)
  gemm256<0, 2, 512, 2048, 2><<<dim3(256), 512, 0, stream>>>(mid, wt_ff2, f2o, nullptr,
                                                             nullptr, nullptr);
  // LN2: h1b + f2o_a + f2o_b + b_ff2 -> out (f32)
  resid_ln<true, true, false, true><<<4096, 256, 0, stream>>>(nullptr, h1b, f2o,
                                                              f2o + (size_t)Mrows * 512,
                                                              b_ff2, g2, b2, out, nullptr);
}

// Round 5
// 332.219 us; speedup vs baseline: 1.0045x; 1.0045x over previous
//
#include <hip/hip_runtime.h>
#include <cmath>

// ---------------------------------------------------------------- types
typedef __bf16 bf16x8 __attribute__((ext_vector_type(8)));
typedef __bf16 bf16x4 __attribute__((ext_vector_type(4)));
typedef float  floatx4 __attribute__((ext_vector_type(4)));

#define LN_EPS 1e-5f
#define INV_TEMP 0.125f   // 1/sqrt(64)

// B=32 S=512 D=512 H=8 DK=DV=64 DFF=2048, M = B*S = 16384
static const int Mrows = 16384;

__device__ __forceinline__ void gload_lds16(const void* g, void* l) {
  __builtin_amdgcn_global_load_lds(
      (const __attribute__((address_space(1))) void*)g,
      (__attribute__((address_space(3))) void*)l, 16, 0, 0);
}

// ---------------------------------------------------------------- fused prep: x->bf16 + 6 weight transposes
__global__ __launch_bounds__(256) void prep_kernel(const float* __restrict__ x, __bf16* __restrict__ xb,
                                                   const float* __restrict__ wq, const float* __restrict__ wk,
                                                   const float* __restrict__ wv, const float* __restrict__ wo,
                                                   const float* __restrict__ wff1, const float* __restrict__ wff2,
                                                   __bf16* __restrict__ tq, __bf16* __restrict__ tk,
                                                   __bf16* __restrict__ tv, __bf16* __restrict__ to_,
                                                   __bf16* __restrict__ tff1, __bf16* __restrict__ tff2) {
  const int bid = blockIdx.x, tid = threadIdx.x;
  if (bid < 8192) {
    int i = bid * 256 + tid;
    float4 v = ((const float4*)x)[i];
    __bf16* d = xb + i * 4;
    d[0] = (__bf16)v.x; d[1] = (__bf16)v.y; d[2] = (__bf16)v.z; d[3] = (__bf16)v.w;
    return;
  }
  __shared__ __bf16 til[64][72];
  int t = bid - 8192;
  const float* src; __bf16* dst; int R, C, bx, by;
  if (t < 256) {
    int w = t >> 6, tt = t & 63;
    const float* srcs[4] = {wq, wk, wv, wo};
    __bf16* dsts[4] = {tq, tk, tv, to_};
    src = srcs[w]; dst = dsts[w]; R = 512; C = 512; bx = tt & 7; by = tt >> 3;
  } else if (t < 512) {
    int tt = t - 256;
    src = wff1; dst = tff1; R = 512; C = 2048; bx = tt & 31; by = tt >> 5;
  } else {
    int tt = t - 512;
    src = wff2; dst = tff2; R = 2048; C = 512; bx = tt & 7; by = tt >> 3;
  }
  const float* s = src + (size_t)(by * 64) * C + bx * 64;
  int r = tid >> 4, c4 = (tid & 15) * 4;
  for (int p = 0; p < 4; ++p) {
    int rr = r + p * 16;
    float4 v = *(const float4*)(s + (size_t)rr * C + c4);
    til[c4 + 0][rr] = (__bf16)v.x;
    til[c4 + 1][rr] = (__bf16)v.y;
    til[c4 + 2][rr] = (__bf16)v.z;
    til[c4 + 3][rr] = (__bf16)v.w;
  }
  __syncthreads();
  __bf16* d = dst + (size_t)(bx * 64) * R + by * 64;
  int orow = tid >> 3, oc8 = (tid & 7) * 8;
  for (int p = 0; p < 2; ++p) {
    int rr = orow + p * 32;
    *(bf16x8*)(d + (size_t)rr * R + oc8) = *(const bf16x8*)(&til[rr][oc8]);
  }
}

// ---------------------------------------------------------------- 256^2 8-wave GEMM, 4-slot K-half ring
// Tile 256x256, 512 threads (waves 2Mx4N). LDS = 4 slots x 32KB; slot = K-half
// (K=32): A[256x32] 16KB + B[256x32] 16KB. Pair-line layout: 128B line p holds
// rows {2p,2p+1}; 16B slot s holds (row&1 = s>>2, kseg = (s&3)^(p&3)).
//   -> read slots distinct within every aligned 8-lane group: 0 bank conflicts.
// Phase h: vmcnt(4) -> barrier -> READF(slot h+1 -> other reg set) ->
//          STAGE(slot h+3) -> 32 MFMA on current set (setprio).
// MFMA consumes regs loaded LAST phase => ds_read overlaps MFMA. vmcnt ladder:
// 4 steady, 0 at NTH-2, none at NTH-1. Stage at phase h writes slot (h-1)&3,
// whose reads were issued at phase h-2 and retired by the phase-h barrier.
// EPI: 0 plain bf16, 2 bias+relu, 4 QKV (inverse q/k norms + V-transpose).
// NKS>1 = split-K, slice ks writes Cv + ks*M*NDIM.
template <int EPI, int NBN, int NDIM, int KDIM, int NKS>
__global__ __launch_bounds__(512, 2) void gemm256(const __bf16* __restrict__ A,
                                                  const __bf16* __restrict__ Bt,
                                                  __bf16* __restrict__ Cv,
                                                  const float* __restrict__ bias,
                                                  float* __restrict__ norms,
                                                  __bf16* __restrict__ vtg) {
  __shared__ __align__(16) char smem[131072];
  const int tid = threadIdx.x;
  const int wave = tid >> 6, lane = tid & 63;
  const int l15 = lane & 15, quad = lane >> 4;
  const int wm = wave >> 2, wn = wave & 3;

  constexpr int NBM = Mrows / 256;          // 64
  constexpr int NBLK = NBM * NBN * NKS;     // divisible by 8 for all instantiations
  constexpr int KS = KDIM / NKS;
  constexpr int NTH = KS / 32;              // K-half count (8/16/32 here, all even)

  int id = blockIdx.x;
  int t = (id & 7) * (NBLK >> 3) + (id >> 3);   // XCD-chunked bijective swizzle
  const int ks = t / (NBM * NBN);
  t -= ks * (NBM * NBN);
  const int nblk = t % NBN, mblk = t / NBN;
  const int m0 = mblk * 256, n0 = nblk * 256;
  const __bf16* Ab = A + (size_t)ks * KS;
  const __bf16* Bb = Bt + (size_t)ks * KS;
  __bf16* Cw = Cv + (size_t)ks * Mrows * NDIM;
  (void)bias;

  // ---- stage mapping: waves 0-3 stage A (rows wq*64+[0,64)), waves 4-7 B.
  // batch j = 16 rows = 8 lines = 1KB. lane l -> line l>>3, phys slot l&7.
  // content of phys slot s at line p: row 2p+(s>>2), kseg (s&3)^(p&3);
  // p&3 == (l>>3)&3 (batch line bases are 0 mod 4).
  const int wq = wave & 3, isB = wave >> 2;
  const int l3 = lane >> 3, s_ = lane & 7;
  const int rowst = wq * 64 + l3 * 2 + (s_ >> 2);
  const int ksw = (s_ & 3) ^ (l3 & 3);
  const __bf16* sbase = (isB ? Bb + (size_t)(n0 + rowst) * KDIM
                             : Ab + (size_t)(m0 + rowst) * KDIM) + ksw * 8;
  const int ldob = isB * 16384 + wq * 4096 + lane * 16;

  // ---- fragment read: row base+l15, kseg=quad ->
  // byte = line*128 + ((row&1)*4 + (quad^(line&3)))*16 ; line&3 == (l15>>1)&3
  const int rsw = (l15 >> 1) * 128 + (((l15 & 1) * 4 + (quad ^ ((l15 >> 1) & 3))) * 16);
  const int aoff = wm * 8192;           // wm*128 rows = wm*64 lines
  const int boff = 16384 + wn * 4096;   // wn*64 rows = wn*32 lines

  floatx4 zero = {0.f, 0.f, 0.f, 0.f};
  floatx4 acc[8][4];
#pragma unroll
  for (int i = 0; i < 8; ++i)
#pragma unroll
    for (int j = 0; j < 4; ++j) acc[i][j] = zero;

  bf16x8 fA0[8], fB0[4], fA1[8], fB1[4];   // two static fragment sets (rule #20)

#define STAGEH(h)                                                            \
  {                                                                          \
    _Pragma("unroll") for (int j = 0; j < 4; ++j)                            \
        gload_lds16(sbase + (size_t)j * (16 * KDIM) + (h) * 32,              \
                    smem + ((h) & 3) * 32768 + ldob + j * 1024);             \
  }

#define READF(S, h)                                                          \
  {                                                                          \
    const char* sp = smem + ((h) & 3) * 32768;                               \
    _Pragma("unroll") for (int i = 0; i < 8; ++i)                            \
      fA##S[i] = *(const bf16x8*)(sp + aoff + i * 1024 + rsw);               \
    _Pragma("unroll") for (int j = 0; j < 4; ++j)                            \
      fB##S[j] = *(const bf16x8*)(sp + boff + j * 1024 + rsw);               \
  }

#define MFMAS(S)                                                             \
  {                                                                          \
    __builtin_amdgcn_s_setprio(1);                                           \
    _Pragma("unroll") for (int i = 0; i < 8; ++i)                            \
      _Pragma("unroll") for (int j = 0; j < 4; ++j)                          \
        acc[i][j] = __builtin_amdgcn_mfma_f32_16x16x32_bf16(fA##S[i], fB##S[j], \
                                                            acc[i][j], 0, 0, 0); \
    __builtin_amdgcn_s_setprio(0);                                           \
  }

#define PHASE(h, C, N, VM, DOPF, DOSTAGE)                                    \
  {                                                                          \
    if (DOPF) {                                                              \
      asm volatile("s_waitcnt vmcnt(" #VM ")" ::: "memory");                 \
      __builtin_amdgcn_s_barrier();                                          \
      READF(N, (h) + 1);                                                     \
    }                                                                        \
    if (DOSTAGE) STAGEH((h) + 3);                                            \
    MFMAS(C);                                                                \
  }

  // prologue: stage slots 0,1,2; wait own stage-0 (vmcnt(8)), barrier (=> all
  // waves' stage-0 complete), preload fragments of slot 0 into set 0.
  STAGEH(0); STAGEH(1); STAGEH(2);
  asm volatile("s_waitcnt vmcnt(8)" ::: "memory");
  __builtin_amdgcn_s_barrier();
  READF(0, 0);

  for (int h2 = 0; h2 < (NTH - 4) / 2; ++h2) {
    int h = h2 * 2;
    PHASE(h,     0, 1, 4, 1, 1);
    PHASE(h + 1, 1, 0, 4, 1, 1);
  }
  PHASE(NTH - 4, 0, 1, 4, 1, 1);   // stages slot NTH-1
  PHASE(NTH - 3, 1, 0, 4, 1, 0);
  PHASE(NTH - 2, 0, 1, 0, 1, 0);
  MFMAS(1);                        // phase NTH-1

#undef STAGEH
#undef READF
#undef MFMAS
#undef PHASE

  if (EPI == 4) {
    int head_global = (n0 + wn * 64) >> 6;
    int kind = head_global >> 3;          // block-uniform: 0=q 1=k 2=v
    if (kind < 2) {
      // fused INVERSE q/k norms; then fall through to the normal C write
      int h = head_global & 7;
#pragma unroll
      for (int ii = 0; ii < 8; ++ii)
#pragma unroll
        for (int r = 0; r < 4; ++r) {
          float sq = 0.f;
#pragma unroll
          for (int jj = 0; jj < 4; ++jj) {
            float v = acc[ii][jj][r];
            sq += v * v;
          }
          for (int m = 1; m < 16; m <<= 1) sq += __shfl_xor(sq, m, 64);
          if (l15 == 0) {
            int arow = m0 + wm * 128 + ii * 16 + quad * 4 + r;
            int bb = arow >> 9, ss = arow & 511;
            norms[kind * 131072 + ((bb << 3) + h) * 512 + ss] = rsqrtf(sq);
          }
        }
    } else {
      // V blocks: transpose through LDS straight into vtg[bh][d][s]
      const int PADT = 136;
      __bf16* Ct = (__bf16*)smem;     // [256 cols][128 rows-of-half + pad]
      int bb = m0 >> 9, s0r = m0 & 511;
#pragma unroll
      for (int hh = 0; hh < 2; ++hh) {
        __builtin_amdgcn_s_barrier();
        if (wm == hh) {
#pragma unroll
          for (int ii = 0; ii < 8; ++ii)
#pragma unroll
            for (int jj = 0; jj < 4; ++jj) {
              bf16x4 pk;
#pragma unroll
              for (int r = 0; r < 4; ++r) pk[r] = (__bf16)acc[ii][jj][r];
              *(bf16x4*)(Ct + (wn * 64 + jj * 16 + l15) * PADT + ii * 16 + quad * 4) = pk;
            }
        }
        __builtin_amdgcn_s_barrier();
#pragma unroll
        for (int p = 0; p < 8; ++p) {
          int c = p * 32 + (tid >> 4);        // local col 0..255 (d within 4 heads)
          int s8 = (tid & 15) * 8;            // s-offset within half
          int h = ((n0 + c) >> 6) & 7, d = c & 63;
          *(bf16x8*)(vtg + ((size_t)(((bb << 3) + h) * 64 + d)) * 512 + s0r + hh * 128 + s8) =
              *(const bf16x8*)(Ct + c * PADT + s8);
        }
      }
      return;
    }
  }

  // normal epilogue: per 128-row half through LDS, wide stores
  const int PADC = 264;
  __bf16* Cs = (__bf16*)smem;
  float bv[4];
  if (EPI == 2) {
#pragma unroll
    for (int j = 0; j < 4; ++j) bv[j] = bias[n0 + wn * 64 + j * 16 + l15];
  }
#pragma unroll
  for (int hh = 0; hh < 2; ++hh) {
    __builtin_amdgcn_s_barrier();
    if (wm == hh) {
#pragma unroll
      for (int i = 0; i < 8; ++i)
#pragma unroll
        for (int j = 0; j < 4; ++j)
#pragma unroll
          for (int r = 0; r < 4; ++r) {
            float v = acc[i][j][r];
            if (EPI == 2) {
              v += bv[j];
              v = v > 0.f ? v : 0.f;
            }
            Cs[(i * 16 + quad * 4 + r) * PADC + wn * 64 + j * 16 + l15] = (__bf16)v;
          }
    }
    __builtin_amdgcn_s_barrier();
#pragma unroll
    for (int p = 0; p < 8; ++p) {
      int rowl = p * 16 + (tid >> 5);
      int c8 = (tid & 31) * 8;
      *(bf16x8*)(Cw + (size_t)(m0 + hh * 128 + rowl) * NDIM + n0 + c8) =
          *(const bf16x8*)(Cs + rowl * PADC + c8);
    }
  }
}

// ---------------------------------------------------------------- attention
__global__ __launch_bounds__(256) void attn_kernel(const __bf16* __restrict__ qkv,
                                                   const __bf16* __restrict__ vtg,
                                                   const float* __restrict__ norms,
                                                   __bf16* __restrict__ out) {
  __shared__ __align__(16) __bf16 Ks[64 * 64];   // [sk][d]
  __shared__ __align__(16) __bf16 Vs[64 * 64];   // [d][sk]
  __shared__ __align__(16) __bf16 P2[4][16 * 72];
  const int tid = threadIdx.x, wave = tid >> 6, lane = tid & 63;
  const int l15 = lane & 15, quad = lane >> 4;
  const int bh = blockIdx.x & 255;
  const int qq = blockIdx.x >> 8;
  const int b = bh >> 3, h = bh & 7;
  const int qbase = qq * 128 + wave * 32;
  const int rs = lane >> 3;
  const int swz_st = ((lane & 7) ^ rs) * 8;
  const int s7 = l15 & 7;

  const __bf16* Qb = qkv + (size_t)(b * 512) * 1536 + h * 64;
  const __bf16* Kb = Qb + 512;
  const __bf16* Vtb = vtg + (size_t)bh * 32768;
  const float* nkinv = norms + 131072 + bh * 512;
  const float* nqinv = norms + bh * 512;
  __bf16* Pw = P2[wave];

  bf16x8 aq[2][2];
  float cq[2];
  for (int ch = 0; ch < 2; ++ch) {
    int qrow = qbase + ch * 16;
    aq[ch][0] = *(const bf16x8*)(Qb + (size_t)(qrow + l15) * 1536 + quad * 8);
    aq[ch][1] = *(const bf16x8*)(Qb + (size_t)(qrow + l15) * 1536 + 32 + quad * 8);
    cq[ch] = nqinv[qrow + l15] * INV_TEMP;
  }

  floatx4 zero = {0.f, 0.f, 0.f, 0.f};
  floatx4 o[2][4];
  float lsum[2] = {0.f, 0.f};
  for (int ch = 0; ch < 2; ++ch)
    for (int jd = 0; jd < 4; ++jd) o[ch][jd] = zero;

  for (int kt = 0; kt < 8; ++kt) {
    int s0 = kt * 64;
    __syncthreads();
    for (int c = 0; c < 4; ++c) {
      int g = wave * 4 + c;
      const __bf16* src;
      __bf16* dst;
      if (g < 8) {
        int sk = g * 8 + rs;
        src = Kb + (size_t)(s0 + sk) * 1536 + swz_st;
        dst = Ks + g * 512;
      } else {
        int g2 = g - 8;
        int d = g2 * 8 + rs;
        src = Vtb + (size_t)d * 512 + s0 + swz_st;
        dst = Vs + g2 * 512;
      }
      gload_lds16(src, dst + lane * 8);
    }
    __syncthreads();

    for (int ch = 0; ch < 2; ++ch) {
      // S^T: 64 sk x 16 q ; lane -> (sk = j*16+quad*4+r, q = l15)
      floatx4 z[4];
      for (int j = 0; j < 4; ++j) {
        int r64 = (j * 16 + l15) * 64;
        bf16x8 k0 = *(const bf16x8*)(Ks + r64 + ((quad ^ s7) * 8));
        bf16x8 k1 = *(const bf16x8*)(Ks + r64 + (((4 + quad) ^ s7) * 8));
        floatx4 zz = zero;
        zz = __builtin_amdgcn_mfma_f32_16x16x32_bf16(k0, aq[ch][0], zz, 0, 0, 0);
        zz = __builtin_amdgcn_mfma_f32_16x16x32_bf16(k1, aq[ch][1], zz, 0, 0, 0);
        z[j] = zz;
      }
      for (int j = 0; j < 4; ++j) {
        floatx4 nk4 = *(const floatx4*)(nkinv + s0 + j * 16 + quad * 4);
        bf16x4 pk;
        for (int r = 0; r < 4; ++r) {
          float p = __expf(z[j][r] * cq[ch] * nk4[r]);
          lsum[ch] += p;
          pk[r] = (__bf16)p;
        }
        *(bf16x4*)(Pw + l15 * 72 + j * 16 + quad * 4) = pk;
      }
      bf16x8 ap0 = *(const bf16x8*)(Pw + l15 * 72 + quad * 8);
      bf16x8 ap1 = *(const bf16x8*)(Pw + l15 * 72 + 32 + quad * 8);
      for (int jd = 0; jd < 4; ++jd) {
        int r64 = (jd * 16 + l15) * 64;
        bf16x8 v0 = *(const bf16x8*)(Vs + r64 + ((quad ^ s7) * 8));
        bf16x8 v1 = *(const bf16x8*)(Vs + r64 + (((4 + quad) ^ s7) * 8));
        o[ch][jd] = __builtin_amdgcn_mfma_f32_16x16x32_bf16(v0, ap0, o[ch][jd], 0, 0, 0);
        o[ch][jd] = __builtin_amdgcn_mfma_f32_16x16x32_bf16(v1, ap1, o[ch][jd], 0, 0, 0);
      }
    }
  }

  for (int ch = 0; ch < 2; ++ch) {
    float s = lsum[ch];
    s += __shfl_xor(s, 16, 64);
    s += __shfl_xor(s, 32, 64);
    float inv = __builtin_amdgcn_rcpf(s);
    int q = qbase + ch * 16 + l15;
    __bf16* op = out + (size_t)(b * 512 + q) * 512 + h * 64;
    for (int jd = 0; jd < 4; ++jd) {
      bf16x4 pk;
      for (int r = 0; r < 4; ++r) pk[r] = (__bf16)(o[ch][jd][r] * inv);
      *(bf16x4*)(op + jd * 16 + quad * 4) = pk;
    }
  }
}

// ---------------------------------------------------------------- residual + layernorm
template <bool X1BF, bool WF, bool WB, bool DUAL>
__global__ __launch_bounds__(256) void resid_ln(const float* __restrict__ X1f,
                                                const __bf16* __restrict__ X1b,
                                                const __bf16* __restrict__ X2,
                                                const __bf16* __restrict__ X2b,
                                                const float* __restrict__ bias,
                                                const float* __restrict__ g,
                                                const float* __restrict__ be,
                                                float* __restrict__ outf,
                                                __bf16* __restrict__ outb) {
  int row = blockIdx.x * 4 + (threadIdx.x >> 6);
  int lane = threadIdx.x & 63;
  float v[8];
  bf16x8 b8 = *(const bf16x8*)(X2 + (size_t)row * 512 + lane * 8);
  if (X1BF) {
    bf16x8 a = *(const bf16x8*)(X1b + (size_t)row * 512 + lane * 8);
    for (int i = 0; i < 8; ++i) v[i] = (float)a[i] + (float)b8[i];
  } else {
    const float4* r1 = (const float4*)(X1f + (size_t)row * 512);
    float4 a0 = r1[lane * 2], a1 = r1[lane * 2 + 1];
    v[0] = a0.x; v[1] = a0.y; v[2] = a0.z; v[3] = a0.w;
    v[4] = a1.x; v[5] = a1.y; v[6] = a1.z; v[7] = a1.w;
    for (int i = 0; i < 8; ++i) v[i] += (float)b8[i];
  }
  if (DUAL) {
    bf16x8 c8 = *(const bf16x8*)(X2b + (size_t)row * 512 + lane * 8);
    for (int i = 0; i < 8; ++i) v[i] += (float)c8[i];
  }
  if (bias) {
    const float* bp = bias + lane * 8;
    for (int i = 0; i < 8; ++i) v[i] += bp[i];
  }
  float s = 0.f, sq = 0.f;
  for (int i = 0; i < 8; ++i) {
    s += v[i];
    sq += v[i] * v[i];
  }
  for (int m = 1; m < 64; m <<= 1) {
    s += __shfl_xor(s, m, 64);
    sq += __shfl_xor(sq, m, 64);
  }
  float mean = s * (1.f / 512.f);
  float var = sq * (1.f / 512.f) - mean * mean;
  float rstd = rsqrtf(var + LN_EPS);
  const float* gp = g + lane * 8;
  const float* bp2 = be + lane * 8;
  float o[8];
  for (int i = 0; i < 8; ++i) o[i] = (v[i] - mean) * rstd * gp[i] + bp2[i];
  if (WF) {
    float4 w0 = {o[0], o[1], o[2], o[3]}, w1 = {o[4], o[5], o[6], o[7]};
    ((float4*)(outf + (size_t)row * 512))[lane * 2] = w0;
    ((float4*)(outf + (size_t)row * 512))[lane * 2 + 1] = w1;
  }
  if (WB) {
    __bf16 tmp[8];
    for (int i = 0; i < 8; ++i) tmp[i] = (__bf16)o[i];
    *(bf16x8*)(outb + (size_t)row * 512 + lane * 8) = *(bf16x8*)tmp;
  }
}

// ---------------------------------------------------------------- launcher
extern "C" void kernel_launch(void* const* d_in, const int* in_sizes, int n_in,
                              void* d_out, int out_size, void* d_ws, size_t ws_size,
                              hipStream_t stream) {
  const float* x     = (const float*)d_in[0];
  const float* w_q   = (const float*)d_in[1];
  const float* w_k   = (const float*)d_in[2];
  const float* w_v   = (const float*)d_in[3];
  const float* w_o   = (const float*)d_in[4];
  const float* w_ff1 = (const float*)d_in[5];
  const float* b_ff1 = (const float*)d_in[6];
  const float* w_ff2 = (const float*)d_in[7];
  const float* b_ff2 = (const float*)d_in[8];
  const float* g1    = (const float*)d_in[9];
  const float* b1    = (const float*)d_in[10];
  const float* g2    = (const float*)d_in[11];
  const float* b2    = (const float*)d_in[12];
  float* out = (float*)d_out;

  char* ws = (char*)d_ws;
  size_t off = 0;
  auto alloc = [&](size_t bytes) -> void* {
    void* p = ws + off;
    off += (bytes + 255) & ~(size_t)255;
    return p;
  };
  __bf16* xb     = (__bf16*)alloc((size_t)Mrows * 512 * 2);
  __bf16* wt_qkv = (__bf16*)alloc((size_t)1536 * 512 * 2);
  __bf16* wt_o   = (__bf16*)alloc((size_t)512 * 512 * 2);
  __bf16* wt_ff1 = (__bf16*)alloc((size_t)2048 * 512 * 2);
  __bf16* wt_ff2 = (__bf16*)alloc((size_t)512 * 2048 * 2);
  __bf16* qkv    = (__bf16*)alloc((size_t)Mrows * 1536 * 2);
  float*  norms  = (float*)alloc((size_t)262144 * 4);
  __bf16* attn   = (__bf16*)alloc((size_t)Mrows * 512 * 2);
  __bf16* projb  = (__bf16*)alloc((size_t)Mrows * 512 * 2);   // contiguous after attn
  __bf16* h1b    = (__bf16*)alloc((size_t)Mrows * 512 * 2);
  __bf16* mid    = (__bf16*)alloc((size_t)Mrows * 2048 * 2);
  __bf16* vtg    = mid;            // alias: vtg dead before w_o writes mid
  __bf16* wo_p   = mid;            // w_o split-K partials: mid + {0, M*512}
  __bf16* f2o    = attn;           // alias: attn dead after w_o GEMM; slice1 -> projb (dead)

  prep_kernel<<<8960, 256, 0, stream>>>(x, xb, w_q, w_k, w_v, w_o, w_ff1, w_ff2,
                                        wt_qkv, wt_qkv + 512 * 512, wt_qkv + 2 * 512 * 512,
                                        wt_o, wt_ff1, wt_ff2);

  // QKV (fused inverse norms + V-transpose into vtg), grid 64x6=384
  gemm256<4, 6, 1536, 512, 1><<<dim3(384), 512, 0, stream>>>(xb, wt_qkv, qkv, nullptr,
                                                             norms, vtg);
  attn_kernel<<<dim3(1024), 256, 0, stream>>>(qkv, vtg, norms, attn);
  // w_o proj -> two bf16 split-K partials into mid (grid 64x2x2=256)
  gemm256<0, 2, 512, 512, 2><<<dim3(256), 512, 0, stream>>>(attn, wt_o, wo_p, nullptr,
                                                            nullptr, nullptr);
  // LN1: x + wo_a + wo_b -> h1b (bf16)
  resid_ln<false, false, true, true><<<4096, 256, 0, stream>>>(x, nullptr, wo_p,
                                                               wo_p + (size_t)Mrows * 512,
                                                               nullptr, g1, b1, nullptr, h1b);
  // FFN1 (+bias, relu): grid 64x8=512
  gemm256<2, 8, 2048, 512, 1><<<dim3(512), 512, 0, stream>>>(h1b, wt_ff1, mid, b_ff1,
                                                             nullptr, nullptr);
  // FFN2 -> two bf16 split-K partials (grid 64x2x2=256)
  gemm256<0, 2, 512, 2048, 2><<<dim3(256), 512, 0, stream>>>(mid, wt_ff2, f2o, nullptr,
                                                             nullptr, nullptr);
  // LN2: h1b + f2o_a + f2o_b + b_ff2 -> out (f32)
  resid_ln<true, true, false, true><<<4096, 256, 0, stream>>>(nullptr, h1b, f2o,
                                                              f2o + (size_t)Mrows * 512,
                                                              b_ff2, g2, b2, out, nullptr);
}

// Round 6
// 331.469 us; speedup vs baseline: 1.0067x; 1.0023x over previous
//
#include <hip/hip_runtime.h>
#include <cmath>

// ---------------------------------------------------------------- types
typedef __bf16 bf16x8 __attribute__((ext_vector_type(8)));
typedef __bf16 bf16x4 __attribute__((ext_vector_type(4)));
typedef float  floatx4 __attribute__((ext_vector_type(4)));

#define LN_EPS 1e-5f
#define INV_TEMP 0.125f   // 1/sqrt(64)

// B=32 S=512 D=512 H=8 DK=DV=64 DFF=2048, M = B*S = 16384
static const int Mrows = 16384;

__device__ __forceinline__ void gload_lds16(const void* g, void* l) {
  __builtin_amdgcn_global_load_lds(
      (const __attribute__((address_space(1))) void*)g,
      (__attribute__((address_space(3))) void*)l, 16, 0, 0);
}

// ---------------------------------------------------------------- fused prep: x->bf16 + 6 weight transposes
__global__ __launch_bounds__(256) void prep_kernel(const float* __restrict__ x, __bf16* __restrict__ xb,
                                                   const float* __restrict__ wq, const float* __restrict__ wk,
                                                   const float* __restrict__ wv, const float* __restrict__ wo,
                                                   const float* __restrict__ wff1, const float* __restrict__ wff2,
                                                   __bf16* __restrict__ tq, __bf16* __restrict__ tk,
                                                   __bf16* __restrict__ tv, __bf16* __restrict__ to_,
                                                   __bf16* __restrict__ tff1, __bf16* __restrict__ tff2) {
  const int bid = blockIdx.x, tid = threadIdx.x;
  if (bid < 8192) {
    int i = bid * 256 + tid;
    float4 v = ((const float4*)x)[i];
    __bf16* d = xb + i * 4;
    d[0] = (__bf16)v.x; d[1] = (__bf16)v.y; d[2] = (__bf16)v.z; d[3] = (__bf16)v.w;
    return;
  }
  __shared__ __bf16 til[64][72];
  int t = bid - 8192;
  const float* src; __bf16* dst; int R, C, bx, by;
  if (t < 256) {
    int w = t >> 6, tt = t & 63;
    const float* srcs[4] = {wq, wk, wv, wo};
    __bf16* dsts[4] = {tq, tk, tv, to_};
    src = srcs[w]; dst = dsts[w]; R = 512; C = 512; bx = tt & 7; by = tt >> 3;
  } else if (t < 512) {
    int tt = t - 256;
    src = wff1; dst = tff1; R = 512; C = 2048; bx = tt & 31; by = tt >> 5;
  } else {
    int tt = t - 512;
    src = wff2; dst = tff2; R = 2048; C = 512; bx = tt & 7; by = tt >> 3;
  }
  const float* s = src + (size_t)(by * 64) * C + bx * 64;
  int r = tid >> 4, c4 = (tid & 15) * 4;
  for (int p = 0; p < 4; ++p) {
    int rr = r + p * 16;
    float4 v = *(const float4*)(s + (size_t)rr * C + c4);
    til[c4 + 0][rr] = (__bf16)v.x;
    til[c4 + 1][rr] = (__bf16)v.y;
    til[c4 + 2][rr] = (__bf16)v.z;
    til[c4 + 3][rr] = (__bf16)v.w;
  }
  __syncthreads();
  __bf16* d = dst + (size_t)(bx * 64) * R + by * 64;
  int orow = tid >> 3, oc8 = (tid & 7) * 8;
  for (int p = 0; p < 2; ++p) {
    int rr = orow + p * 32;
    *(bf16x8*)(d + (size_t)rr * R + oc8) = *(const bf16x8*)(&til[rr][oc8]);
  }
}

// ---------------------------------------------------------------- 256^2 8-wave GEMM, 4-slot K-half ring
// Tile 256x256, 512 threads (waves 2Mx4N). LDS = 4 slots x 32KB; slot = K-half
// (K=32): A[256x32] 16KB + B[256x32] 16KB, as 32 chunks of 1KB (16 rows x 32K).
// Chunk content map (conflict-free): stage lane l holds (row=l>>2, kseg=(l&3)^(l>>4))
// at byte l*16; read of (r, q=quad) at byte 64r + 16*(q^(r>>2)). Within each
// 16-lane quarter slot%16 = 4*(r&3) + (q^(r>>2)) is bijective -> 0 conflicts.
// Phase h: vmcnt(8) -> barrier -> 12 ds_read_b128 -> stage slot h+3 (4 loads) ->
//          lgkmcnt(0) -> setprio(1) 32 MFMA setprio(0).
// vmcnt in-order retire: <=8 outstanding = newest 2 slots => slot h confirmed.
// Barrier-top also retires all slot-(h+4==h) readers before restage. Tail 8,8,4,0.
// EPI: 0 plain bf16, 2 bias+relu, 4 QKV (inverse q/k norms + V-transpose).
// NKS>1 = split-K, slice ks writes Cv + ks*M*NDIM.
template <int EPI, int NBN, int NDIM, int KDIM, int NKS>
__global__ __launch_bounds__(512, 2) void gemm256(const __bf16* __restrict__ A,
                                                  const __bf16* __restrict__ Bt,
                                                  __bf16* __restrict__ Cv,
                                                  const float* __restrict__ bias,
                                                  float* __restrict__ norms,
                                                  __bf16* __restrict__ vtg) {
  __shared__ __align__(16) char smem[131072];
  const int tid = threadIdx.x;
  const int wave = tid >> 6, lane = tid & 63;
  const int l15 = lane & 15, quad = lane >> 4;
  const int wm = wave >> 2, wn = wave & 3;

  constexpr int NBM = Mrows / 256;          // 64
  constexpr int NBLK = NBM * NBN * NKS;     // divisible by 8 for all instantiations
  constexpr int KS = KDIM / NKS;
  constexpr int NTH = KS / 32;              // K-half count (8/16/32 here)

  int id = blockIdx.x;
  int t = (id & 7) * (NBLK >> 3) + (id >> 3);   // XCD-chunked bijective swizzle
  const int ks = t / (NBM * NBN);
  t -= ks * (NBM * NBN);
  const int nblk = t % NBN, mblk = t / NBN;
  const int m0 = mblk * 256, n0 = nblk * 256;
  const __bf16* Ab = A + (size_t)ks * KS;
  const __bf16* Bb = Bt + (size_t)ks * KS;
  __bf16* Cw = Cv + (size_t)ks * Mrows * NDIM;
  (void)bias;

  // ---- stage mapping: waves 0-3 stage A (chunks wq*4+j), waves 4-7 stage B.
  // chunk c covers tile rows c*16..+16; lane l -> row c*16 + (l>>2),
  // kseg (l&3)^(l>>4); LDS dest = slot + isB*16KB + wq*4KB + j*1KB + l*16.
  const int wq = wave & 3, isB = wave >> 2;
  const int rowst = wq * 64 + (lane >> 2);
  const int ksg = (lane & 3) ^ (lane >> 4);
  const __bf16* sbase = (isB ? Bb + (size_t)(n0 + rowst) * KDIM
                             : Ab + (size_t)(m0 + rowst) * KDIM) + ksg * 8;
  const int ldob = isB * 16384 + wq * 4096 + lane * 16;

  // ---- fragment read lane term (bytes): row l15, kseg quad within a chunk
  const int lrt = l15 * 64 + ((quad ^ (l15 >> 2)) * 16);
  const int aoff = wm * 8192;           // A chunks wm*8 .. +8
  const int boff = 16384 + wn * 4096;   // B chunks wn*4 .. +4

  floatx4 zero = {0.f, 0.f, 0.f, 0.f};
  floatx4 acc[8][4];
#pragma unroll
  for (int i = 0; i < 8; ++i)
#pragma unroll
    for (int j = 0; j < 4; ++j) acc[i][j] = zero;

#define STAGEH(h)                                                            \
  {                                                                          \
    _Pragma("unroll") for (int j = 0; j < 4; ++j)                            \
        gload_lds16(sbase + (size_t)j * (16 * KDIM) + (h) * 32,              \
                    smem + ((h) & 3) * 32768 + ldob + j * 1024);             \
  }

#define PHASE(h, VM, DOSTAGE)                                                \
  {                                                                          \
    asm volatile("s_waitcnt vmcnt(" #VM ")" ::: "memory");                   \
    __builtin_amdgcn_s_barrier();                                            \
    const char* slotp = smem + ((h) & 3) * 32768;                            \
    bf16x8 aF[8], bF[4];                                                     \
    _Pragma("unroll") for (int i = 0; i < 8; ++i)                            \
      aF[i] = *(const bf16x8*)(slotp + aoff + i * 1024 + lrt);               \
    _Pragma("unroll") for (int j = 0; j < 4; ++j)                            \
      bF[j] = *(const bf16x8*)(slotp + boff + j * 1024 + lrt);               \
    if (DOSTAGE) STAGEH((h) + 3);                                            \
    asm volatile("s_waitcnt lgkmcnt(0)" ::: "memory");                       \
    __builtin_amdgcn_s_setprio(1);                                           \
    _Pragma("unroll") for (int i = 0; i < 8; ++i)                            \
      _Pragma("unroll") for (int j = 0; j < 4; ++j)                          \
        acc[i][j] = __builtin_amdgcn_mfma_f32_16x16x32_bf16(aF[i], bF[j],    \
                                                            acc[i][j], 0, 0, 0); \
    __builtin_amdgcn_s_setprio(0);                                           \
  }

  // prologue: stage slots 0,1,2 (12 loads outstanding)
  STAGEH(0); STAGEH(1); STAGEH(2);

  for (int h = 0; h <= NTH - 4; ++h) PHASE(h, 8, 1);
  PHASE(NTH - 3, 8, 0);
  PHASE(NTH - 2, 4, 0);
  PHASE(NTH - 1, 0, 0);

#undef STAGEH
#undef PHASE

  if (EPI == 4) {
    int head_global = (n0 + wn * 64) >> 6;
    int kind = head_global >> 3;          // block-uniform: 0=q 1=k 2=v
    if (kind < 2) {
      // fused INVERSE q/k norms; then fall through to the normal C write
      int h = head_global & 7;
#pragma unroll
      for (int ii = 0; ii < 8; ++ii)
#pragma unroll
        for (int r = 0; r < 4; ++r) {
          float sq = 0.f;
#pragma unroll
          for (int jj = 0; jj < 4; ++jj) {
            float v = acc[ii][jj][r];
            sq += v * v;
          }
          for (int m = 1; m < 16; m <<= 1) sq += __shfl_xor(sq, m, 64);
          if (l15 == 0) {
            int arow = m0 + wm * 128 + ii * 16 + quad * 4 + r;
            int bb = arow >> 9, ss = arow & 511;
            norms[kind * 131072 + ((bb << 3) + h) * 512 + ss] = rsqrtf(sq);
          }
        }
    } else {
      // V blocks: transpose through LDS straight into vtg[bh][d][s]
      const int PADT = 136;
      __bf16* Ct = (__bf16*)smem;     // [256 cols][128 rows-of-half + pad]
      int bb = m0 >> 9, s0r = m0 & 511;
#pragma unroll
      for (int hh = 0; hh < 2; ++hh) {
        __builtin_amdgcn_s_barrier();
        if (wm == hh) {
#pragma unroll
          for (int ii = 0; ii < 8; ++ii)
#pragma unroll
            for (int jj = 0; jj < 4; ++jj) {
              bf16x4 pk;
#pragma unroll
              for (int r = 0; r < 4; ++r) pk[r] = (__bf16)acc[ii][jj][r];
              *(bf16x4*)(Ct + (wn * 64 + jj * 16 + l15) * PADT + ii * 16 + quad * 4) = pk;
            }
        }
        __builtin_amdgcn_s_barrier();
#pragma unroll
        for (int p = 0; p < 8; ++p) {
          int c = p * 32 + (tid >> 4);        // local col 0..255 (d within 4 heads)
          int s8 = (tid & 15) * 8;            // s-offset within half
          int h = ((n0 + c) >> 6) & 7, d = c & 63;
          *(bf16x8*)(vtg + ((size_t)(((bb << 3) + h) * 64 + d)) * 512 + s0r + hh * 128 + s8) =
              *(const bf16x8*)(Ct + c * PADT + s8);
        }
      }
      return;
    }
  }

  // normal epilogue: per 128-row half through LDS, wide stores
  const int PADC = 264;
  __bf16* Cs = (__bf16*)smem;
  float bv[4];
  if (EPI == 2) {
#pragma unroll
    for (int j = 0; j < 4; ++j) bv[j] = bias[n0 + wn * 64 + j * 16 + l15];
  }
#pragma unroll
  for (int hh = 0; hh < 2; ++hh) {
    __builtin_amdgcn_s_barrier();
    if (wm == hh) {
#pragma unroll
      for (int i = 0; i < 8; ++i)
#pragma unroll
        for (int j = 0; j < 4; ++j)
#pragma unroll
          for (int r = 0; r < 4; ++r) {
            float v = acc[i][j][r];
            if (EPI == 2) {
              v += bv[j];
              v = v > 0.f ? v : 0.f;
            }
            Cs[(i * 16 + quad * 4 + r) * PADC + wn * 64 + j * 16 + l15] = (__bf16)v;
          }
    }
    __builtin_amdgcn_s_barrier();
#pragma unroll
    for (int p = 0; p < 8; ++p) {
      int rowl = p * 16 + (tid >> 5);
      int c8 = (tid & 31) * 8;
      *(bf16x8*)(Cw + (size_t)(m0 + hh * 128 + rowl) * NDIM + n0 + c8) =
          *(const bf16x8*)(Cs + rowl * PADC + c8);
    }
  }
}

// ---------------------------------------------------------------- attention
__global__ __launch_bounds__(256) void attn_kernel(const __bf16* __restrict__ qkv,
                                                   const __bf16* __restrict__ vtg,
                                                   const float* __restrict__ norms,
                                                   __bf16* __restrict__ out) {
  __shared__ __align__(16) __bf16 Ks[64 * 64];   // [sk][d]
  __shared__ __align__(16) __bf16 Vs[64 * 64];   // [d][sk]
  __shared__ __align__(16) __bf16 P2[4][16 * 72];
  const int tid = threadIdx.x, wave = tid >> 6, lane = tid & 63;
  const int l15 = lane & 15, quad = lane >> 4;
  const int bh = blockIdx.x & 255;
  const int qq = blockIdx.x >> 8;
  const int b = bh >> 3, h = bh & 7;
  const int qbase = qq * 128 + wave * 32;
  const int rs = lane >> 3;
  const int swz_st = ((lane & 7) ^ rs) * 8;
  const int s7 = l15 & 7;

  const __bf16* Qb = qkv + (size_t)(b * 512) * 1536 + h * 64;
  const __bf16* Kb = Qb + 512;
  const __bf16* Vtb = vtg + (size_t)bh * 32768;
  const float* nkinv = norms + 131072 + bh * 512;
  const float* nqinv = norms + bh * 512;
  __bf16* Pw = P2[wave];

  bf16x8 aq[2][2];
  float cq[2];
  for (int ch = 0; ch < 2; ++ch) {
    int qrow = qbase + ch * 16;
    aq[ch][0] = *(const bf16x8*)(Qb + (size_t)(qrow + l15) * 1536 + quad * 8);
    aq[ch][1] = *(const bf16x8*)(Qb + (size_t)(qrow + l15) * 1536 + 32 + quad * 8);
    cq[ch] = nqinv[qrow + l15] * INV_TEMP;
  }

  floatx4 zero = {0.f, 0.f, 0.f, 0.f};
  floatx4 o[2][4];
  float lsum[2] = {0.f, 0.f};
  for (int ch = 0; ch < 2; ++ch)
    for (int jd = 0; jd < 4; ++jd) o[ch][jd] = zero;

  for (int kt = 0; kt < 8; ++kt) {
    int s0 = kt * 64;
    __syncthreads();
    for (int c = 0; c < 4; ++c) {
      int g = wave * 4 + c;
      const __bf16* src;
      __bf16* dst;
      if (g < 8) {
        int sk = g * 8 + rs;
        src = Kb + (size_t)(s0 + sk) * 1536 + swz_st;
        dst = Ks + g * 512;
      } else {
        int g2 = g - 8;
        int d = g2 * 8 + rs;
        src = Vtb + (size_t)d * 512 + s0 + swz_st;
        dst = Vs + g2 * 512;
      }
      gload_lds16(src, dst + lane * 8);
    }
    __syncthreads();

    for (int ch = 0; ch < 2; ++ch) {
      // S^T: 64 sk x 16 q ; lane -> (sk = j*16+quad*4+r, q = l15)
      floatx4 z[4];
      for (int j = 0; j < 4; ++j) {
        int r64 = (j * 16 + l15) * 64;
        bf16x8 k0 = *(const bf16x8*)(Ks + r64 + ((quad ^ s7) * 8));
        bf16x8 k1 = *(const bf16x8*)(Ks + r64 + (((4 + quad) ^ s7) * 8));
        floatx4 zz = zero;
        zz = __builtin_amdgcn_mfma_f32_16x16x32_bf16(k0, aq[ch][0], zz, 0, 0, 0);
        zz = __builtin_amdgcn_mfma_f32_16x16x32_bf16(k1, aq[ch][1], zz, 0, 0, 0);
        z[j] = zz;
      }
      for (int j = 0; j < 4; ++j) {
        floatx4 nk4 = *(const floatx4*)(nkinv + s0 + j * 16 + quad * 4);
        bf16x4 pk;
        for (int r = 0; r < 4; ++r) {
          float p = __expf(z[j][r] * cq[ch] * nk4[r]);
          lsum[ch] += p;
          pk[r] = (__bf16)p;
        }
        *(bf16x4*)(Pw + l15 * 72 + j * 16 + quad * 4) = pk;
      }
      bf16x8 ap0 = *(const bf16x8*)(Pw + l15 * 72 + quad * 8);
      bf16x8 ap1 = *(const bf16x8*)(Pw + l15 * 72 + 32 + quad * 8);
      for (int jd = 0; jd < 4; ++jd) {
        int r64 = (jd * 16 + l15) * 64;
        bf16x8 v0 = *(const bf16x8*)(Vs + r64 + ((quad ^ s7) * 8));
        bf16x8 v1 = *(const bf16x8*)(Vs + r64 + (((4 + quad) ^ s7) * 8));
        o[ch][jd] = __builtin_amdgcn_mfma_f32_16x16x32_bf16(v0, ap0, o[ch][jd], 0, 0, 0);
        o[ch][jd] = __builtin_amdgcn_mfma_f32_16x16x32_bf16(v1, ap1, o[ch][jd], 0, 0, 0);
      }
    }
  }

  for (int ch = 0; ch < 2; ++ch) {
    float s = lsum[ch];
    s += __shfl_xor(s, 16, 64);
    s += __shfl_xor(s, 32, 64);
    float inv = __builtin_amdgcn_rcpf(s);
    int q = qbase + ch * 16 + l15;
    __bf16* op = out + (size_t)(b * 512 + q) * 512 + h * 64;
    for (int jd = 0; jd < 4; ++jd) {
      bf16x4 pk;
      for (int r = 0; r < 4; ++r) pk[r] = (__bf16)(o[ch][jd][r] * inv);
      *(bf16x4*)(op + jd * 16 + quad * 4) = pk;
    }
  }
}

// ---------------------------------------------------------------- residual + layernorm
template <bool X1BF, bool WF, bool WB, bool DUAL>
__global__ __launch_bounds__(256) void resid_ln(const float* __restrict__ X1f,
                                                const __bf16* __restrict__ X1b,
                                                const __bf16* __restrict__ X2,
                                                const __bf16* __restrict__ X2b,
                                                const float* __restrict__ bias,
                                                const float* __restrict__ g,
                                                const float* __restrict__ be,
                                                float* __restrict__ outf,
                                                __bf16* __restrict__ outb) {
  int row = blockIdx.x * 4 + (threadIdx.x >> 6);
  int lane = threadIdx.x & 63;
  float v[8];
  bf16x8 b8 = *(const bf16x8*)(X2 + (size_t)row * 512 + lane * 8);
  if (X1BF) {
    bf16x8 a = *(const bf16x8*)(X1b + (size_t)row * 512 + lane * 8);
    for (int i = 0; i < 8; ++i) v[i] = (float)a[i] + (float)b8[i];
  } else {
    const float4* r1 = (const float4*)(X1f + (size_t)row * 512);
    float4 a0 = r1[lane * 2], a1 = r1[lane * 2 + 1];
    v[0] = a0.x; v[1] = a0.y; v[2] = a0.z; v[3] = a0.w;
    v[4] = a1.x; v[5] = a1.y; v[6] = a1.z; v[7] = a1.w;
    for (int i = 0; i < 8; ++i) v[i] += (float)b8[i];
  }
  if (DUAL) {
    bf16x8 c8 = *(const bf16x8*)(X2b + (size_t)row * 512 + lane * 8);
    for (int i = 0; i < 8; ++i) v[i] += (float)c8[i];
  }
  if (bias) {
    const float* bp = bias + lane * 8;
    for (int i = 0; i < 8; ++i) v[i] += bp[i];
  }
  float s = 0.f, sq = 0.f;
  for (int i = 0; i < 8; ++i) {
    s += v[i];
    sq += v[i] * v[i];
  }
  for (int m = 1; m < 64; m <<= 1) {
    s += __shfl_xor(s, m, 64);
    sq += __shfl_xor(sq, m, 64);
  }
  float mean = s * (1.f / 512.f);
  float var = sq * (1.f / 512.f) - mean * mean;
  float rstd = rsqrtf(var + LN_EPS);
  const float* gp = g + lane * 8;
  const float* bp2 = be + lane * 8;
  float o[8];
  for (int i = 0; i < 8; ++i) o[i] = (v[i] - mean) * rstd * gp[i] + bp2[i];
  if (WF) {
    float4 w0 = {o[0], o[1], o[2], o[3]}, w1 = {o[4], o[5], o[6], o[7]};
    ((float4*)(outf + (size_t)row * 512))[lane * 2] = w0;
    ((float4*)(outf + (size_t)row * 512))[lane * 2 + 1] = w1;
  }
  if (WB) {
    __bf16 tmp[8];
    for (int i = 0; i < 8; ++i) tmp[i] = (__bf16)o[i];
    *(bf16x8*)(outb + (size_t)row * 512 + lane * 8) = *(bf16x8*)tmp;
  }
}

// ---------------------------------------------------------------- launcher
extern "C" void kernel_launch(void* const* d_in, const int* in_sizes, int n_in,
                              void* d_out, int out_size, void* d_ws, size_t ws_size,
                              hipStream_t stream) {
  const float* x     = (const float*)d_in[0];
  const float* w_q   = (const float*)d_in[1];
  const float* w_k   = (const float*)d_in[2];
  const float* w_v   = (const float*)d_in[3];
  const float* w_o   = (const float*)d_in[4];
  const float* w_ff1 = (const float*)d_in[5];
  const float* b_ff1 = (const float*)d_in[6];
  const float* w_ff2 = (const float*)d_in[7];
  const float* b_ff2 = (const float*)d_in[8];
  const float* g1    = (const float*)d_in[9];
  const float* b1    = (const float*)d_in[10];
  const float* g2    = (const float*)d_in[11];
  const float* b2    = (const float*)d_in[12];
  float* out = (float*)d_out;

  char* ws = (char*)d_ws;
  size_t off = 0;
  auto alloc = [&](size_t bytes) -> void* {
    void* p = ws + off;
    off += (bytes + 255) & ~(size_t)255;
    return p;
  };
  __bf16* xb     = (__bf16*)alloc((size_t)Mrows * 512 * 2);
  __bf16* wt_qkv = (__bf16*)alloc((size_t)1536 * 512 * 2);
  __bf16* wt_o   = (__bf16*)alloc((size_t)512 * 512 * 2);
  __bf16* wt_ff1 = (__bf16*)alloc((size_t)2048 * 512 * 2);
  __bf16* wt_ff2 = (__bf16*)alloc((size_t)512 * 2048 * 2);
  __bf16* qkv    = (__bf16*)alloc((size_t)Mrows * 1536 * 2);
  float*  norms  = (float*)alloc((size_t)262144 * 4);
  __bf16* attn   = (__bf16*)alloc((size_t)Mrows * 512 * 2);
  __bf16* projb  = (__bf16*)alloc((size_t)Mrows * 512 * 2);   // contiguous after attn
  __bf16* h1b    = (__bf16*)alloc((size_t)Mrows * 512 * 2);
  __bf16* mid    = (__bf16*)alloc((size_t)Mrows * 2048 * 2);
  __bf16* vtg    = mid;            // alias: vtg dead before w_o writes mid
  __bf16* wo_p   = mid;            // w_o split-K partials: mid + {0, M*512}
  __bf16* f2o    = attn;           // alias: attn dead after w_o GEMM; slice1 -> projb (dead)

  prep_kernel<<<8960, 256, 0, stream>>>(x, xb, w_q, w_k, w_v, w_o, w_ff1, w_ff2,
                                        wt_qkv, wt_qkv + 512 * 512, wt_qkv + 2 * 512 * 512,
                                        wt_o, wt_ff1, wt_ff2);

  // QKV (fused inverse norms + V-transpose into vtg), grid 64x6=384
  gemm256<4, 6, 1536, 512, 1><<<dim3(384), 512, 0, stream>>>(xb, wt_qkv, qkv, nullptr,
                                                             norms, vtg);
  attn_kernel<<<dim3(1024), 256, 0, stream>>>(qkv, vtg, norms, attn);
  // w_o proj -> two bf16 split-K partials into mid (grid 64x2x2=256)
  gemm256<0, 2, 512, 512, 2><<<dim3(256), 512, 0, stream>>>(attn, wt_o, wo_p, nullptr,
                                                            nullptr, nullptr);
  // LN1: x + wo_a + wo_b -> h1b (bf16)
  resid_ln<false, false, true, true><<<4096, 256, 0, stream>>>(x, nullptr, wo_p,
                                                               wo_p + (size_t)Mrows * 512,
                                                               nullptr, g1, b1, nullptr, h1b);
  // FFN1 (+bias, relu): grid 64x8=512
  gemm256<2, 8, 2048, 512, 1><<<dim3(512), 512, 0, stream>>>(h1b, wt_ff1, mid, b_ff1,
                                                             nullptr, nullptr);
  // FFN2 -> two bf16 split-K partials (grid 64x2x2=256)
  gemm256<0, 2, 512, 2048, 2><<<dim3(256), 512, 0, stream>>>(mid, wt_ff2, f2o, nullptr,
                                                             nullptr, nullptr);
  // LN2: h1b + f2o_a + f2o_b + b_ff2 -> out (f32)
  resid_ln<true, true, false, true><<<4096, 256, 0, stream>>>(nullptr, h1b, f2o,
                                                              f2o + (size_t)Mrows * 512,
                                                              b_ff2, g2, b2, out, nullptr);
}

// Round 7
// 329.472 us; speedup vs baseline: 1.0128x; 1.0061x over previous
//
#include <hip/hip_runtime.h>
#include <cmath>

// ---------------------------------------------------------------- types
typedef __bf16 bf16x8 __attribute__((ext_vector_type(8)));
typedef __bf16 bf16x4 __attribute__((ext_vector_type(4)));
typedef float  floatx4 __attribute__((ext_vector_type(4)));

#define LN_EPS 1e-5f
#define INV_TEMP 0.125f   // 1/sqrt(64)

// B=32 S=512 D=512 H=8 DK=DV=64 DFF=2048, M = B*S = 16384
static const int Mrows = 16384;

__device__ __forceinline__ void gload_lds16(const void* g, void* l) {
  __builtin_amdgcn_global_load_lds(
      (const __attribute__((address_space(1))) void*)g,
      (__attribute__((address_space(3))) void*)l, 16, 0, 0);
}

// ---------------------------------------------------------------- fused prep: x->bf16 + 6 weight transposes
__global__ __launch_bounds__(256) void prep_kernel(const float* __restrict__ x, __bf16* __restrict__ xb,
                                                   const float* __restrict__ wq, const float* __restrict__ wk,
                                                   const float* __restrict__ wv, const float* __restrict__ wo,
                                                   const float* __restrict__ wff1, const float* __restrict__ wff2,
                                                   __bf16* __restrict__ tq, __bf16* __restrict__ tk,
                                                   __bf16* __restrict__ tv, __bf16* __restrict__ to_,
                                                   __bf16* __restrict__ tff1, __bf16* __restrict__ tff2) {
  const int bid = blockIdx.x, tid = threadIdx.x;
  if (bid < 8192) {
    int i = bid * 256 + tid;
    float4 v = ((const float4*)x)[i];
    __bf16* d = xb + i * 4;
    d[0] = (__bf16)v.x; d[1] = (__bf16)v.y; d[2] = (__bf16)v.z; d[3] = (__bf16)v.w;
    return;
  }
  __shared__ __bf16 til[64][72];
  int t = bid - 8192;
  const float* src; __bf16* dst; int R, C, bx, by;
  if (t < 256) {
    int w = t >> 6, tt = t & 63;
    const float* srcs[4] = {wq, wk, wv, wo};
    __bf16* dsts[4] = {tq, tk, tv, to_};
    src = srcs[w]; dst = dsts[w]; R = 512; C = 512; bx = tt & 7; by = tt >> 3;
  } else if (t < 512) {
    int tt = t - 256;
    src = wff1; dst = tff1; R = 512; C = 2048; bx = tt & 31; by = tt >> 5;
  } else {
    int tt = t - 512;
    src = wff2; dst = tff2; R = 2048; C = 512; bx = tt & 7; by = tt >> 3;
  }
  const float* s = src + (size_t)(by * 64) * C + bx * 64;
  int r = tid >> 4, c4 = (tid & 15) * 4;
  for (int p = 0; p < 4; ++p) {
    int rr = r + p * 16;
    float4 v = *(const float4*)(s + (size_t)rr * C + c4);
    til[c4 + 0][rr] = (__bf16)v.x;
    til[c4 + 1][rr] = (__bf16)v.y;
    til[c4 + 2][rr] = (__bf16)v.z;
    til[c4 + 3][rr] = (__bf16)v.w;
  }
  __syncthreads();
  __bf16* d = dst + (size_t)(bx * 64) * R + by * 64;
  int orow = tid >> 3, oc8 = (tid & 7) * 8;
  for (int p = 0; p < 2; ++p) {
    int rr = orow + p * 32;
    *(bf16x8*)(d + (size_t)rr * R + oc8) = *(const bf16x8*)(&til[rr][oc8]);
  }
}

// ---------------------------------------------------------------- 256^2 8-wave GEMM, 4-slot K-half ring
// Tile 256x256, 512 threads (waves 2Mx4N). LDS = 4 slots x 32KB; slot = K-half
// (K=32): A[256x32] 16KB + B[256x32] 16KB. Pair-line layout (R5-verified):
// 128B line p holds rows {2p,2p+1}; 16B slot s -> (row&1 = s>>2, kseg = (s&3)^(p&3)).
// Bank rule (calibrated R1/R4/R5/R6): slot mod 8 bijective within every
// consecutive 8-lane group -> 0 conflicts for ds_read_b128. This layout: lanes
// 8g..8g+7 cover slots {0,4,1,5,2,6,3,7} XOR const -> bijective.
// Phase h: vmcnt(8) -> barrier -> 12 ds_read_b128 -> stage slot h+3 (4 loads) ->
//          lgkmcnt(0) -> setprio(1) 32 MFMA setprio(0).
// vmcnt in-order retire: <=8 outstanding = newest 2 slots => slot h confirmed.
// Barrier-top also retires all slot-(h+4==h) readers before restage. Tail 8,8,4,0.
// EPI: 0 plain bf16, 2 bias+relu, 4 QKV (inverse q/k norms + V-transpose).
// NKS>1 = split-K, slice ks writes Cv + ks*M*NDIM.
template <int EPI, int NBN, int NDIM, int KDIM, int NKS>
__global__ __launch_bounds__(512, 2) void gemm256(const __bf16* __restrict__ A,
                                                  const __bf16* __restrict__ Bt,
                                                  __bf16* __restrict__ Cv,
                                                  const float* __restrict__ bias,
                                                  float* __restrict__ norms,
                                                  __bf16* __restrict__ vtg) {
  __shared__ __align__(16) char smem[131072];
  const int tid = threadIdx.x;
  const int wave = tid >> 6, lane = tid & 63;
  const int l15 = lane & 15, quad = lane >> 4;
  const int wm = wave >> 2, wn = wave & 3;

  constexpr int NBM = Mrows / 256;          // 64
  constexpr int NBLK = NBM * NBN * NKS;     // divisible by 8 for all instantiations
  constexpr int KS = KDIM / NKS;
  constexpr int NTH = KS / 32;              // K-half count (8/16/32 here)

  int id = blockIdx.x;
  int t = (id & 7) * (NBLK >> 3) + (id >> 3);   // XCD-chunked bijective swizzle
  const int ks = t / (NBM * NBN);
  t -= ks * (NBM * NBN);
  const int nblk = t % NBN, mblk = t / NBN;
  const int m0 = mblk * 256, n0 = nblk * 256;
  const __bf16* Ab = A + (size_t)ks * KS;
  const __bf16* Bb = Bt + (size_t)ks * KS;
  __bf16* Cw = Cv + (size_t)ks * Mrows * NDIM;
  (void)bias;

  // ---- stage mapping (R5-verified pair): waves 0-3 stage A (rows wq*64+[0,64)),
  // waves 4-7 B. batch j = 16 rows = 8 lines = 1KB. lane l -> line l>>3,
  // phys slot l&7; content: row = 2*(l>>3) + ((l&7)>>2), kseg = ((l&7)&3)^((l>>3)&3).
  const int wq = wave & 3, isB = wave >> 2;
  const int l3 = lane >> 3, s_ = lane & 7;
  const int rowst = wq * 64 + l3 * 2 + (s_ >> 2);
  const int ksw = (s_ & 3) ^ (l3 & 3);
  const __bf16* sbase = (isB ? Bb + (size_t)(n0 + rowst) * KDIM
                             : Ab + (size_t)(m0 + rowst) * KDIM) + ksw * 8;
  const int ldob = isB * 16384 + wq * 4096 + lane * 16;

  // ---- fragment read lane term (bytes): row l15, kseg quad within a 1KB chunk:
  // line l15>>1, slot (l15&1)*4 + (quad^((l15>>1)&3))
  const int lrt = (l15 >> 1) * 128 + (((l15 & 1) * 4 + (quad ^ ((l15 >> 1) & 3))) * 16);
  const int aoff = wm * 8192;           // A chunks wm*8 .. +8
  const int boff = 16384 + wn * 4096;   // B chunks wn*4 .. +4

  floatx4 zero = {0.f, 0.f, 0.f, 0.f};
  floatx4 acc[8][4];
#pragma unroll
  for (int i = 0; i < 8; ++i)
#pragma unroll
    for (int j = 0; j < 4; ++j) acc[i][j] = zero;

#define STAGEH(h)                                                            \
  {                                                                          \
    _Pragma("unroll") for (int j = 0; j < 4; ++j)                            \
        gload_lds16(sbase + (size_t)j * (16 * KDIM) + (h) * 32,              \
                    smem + ((h) & 3) * 32768 + ldob + j * 1024);             \
  }

#define PHASE(h, VM, DOSTAGE)                                                \
  {                                                                          \
    asm volatile("s_waitcnt vmcnt(" #VM ")" ::: "memory");                   \
    __builtin_amdgcn_s_barrier();                                            \
    const char* slotp = smem + ((h) & 3) * 32768;                            \
    bf16x8 aF[8], bF[4];                                                     \
    _Pragma("unroll") for (int i = 0; i < 8; ++i)                            \
      aF[i] = *(const bf16x8*)(slotp + aoff + i * 1024 + lrt);               \
    _Pragma("unroll") for (int j = 0; j < 4; ++j)                            \
      bF[j] = *(const bf16x8*)(slotp + boff + j * 1024 + lrt);               \
    if (DOSTAGE) STAGEH((h) + 3);                                            \
    asm volatile("s_waitcnt lgkmcnt(0)" ::: "memory");                       \
    __builtin_amdgcn_s_setprio(1);                                           \
    _Pragma("unroll") for (int i = 0; i < 8; ++i)                            \
      _Pragma("unroll") for (int j = 0; j < 4; ++j)                          \
        acc[i][j] = __builtin_amdgcn_mfma_f32_16x16x32_bf16(aF[i], bF[j],    \
                                                            acc[i][j], 0, 0, 0); \
    __builtin_amdgcn_s_setprio(0);                                           \
  }

  // prologue: stage slots 0,1,2 (12 loads outstanding)
  STAGEH(0); STAGEH(1); STAGEH(2);

  for (int h = 0; h <= NTH - 4; ++h) PHASE(h, 8, 1);
  PHASE(NTH - 3, 8, 0);
  PHASE(NTH - 2, 4, 0);
  PHASE(NTH - 1, 0, 0);

#undef STAGEH
#undef PHASE

  if (EPI == 4) {
    int head_global = (n0 + wn * 64) >> 6;
    int kind = head_global >> 3;          // block-uniform: 0=q 1=k 2=v
    if (kind < 2) {
      // fused INVERSE q/k norms; then fall through to the normal C write
      int h = head_global & 7;
#pragma unroll
      for (int ii = 0; ii < 8; ++ii)
#pragma unroll
        for (int r = 0; r < 4; ++r) {
          float sq = 0.f;
#pragma unroll
          for (int jj = 0; jj < 4; ++jj) {
            float v = acc[ii][jj][r];
            sq += v * v;
          }
          for (int m = 1; m < 16; m <<= 1) sq += __shfl_xor(sq, m, 64);
          if (l15 == 0) {
            int arow = m0 + wm * 128 + ii * 16 + quad * 4 + r;
            int bb = arow >> 9, ss = arow & 511;
            norms[kind * 131072 + ((bb << 3) + h) * 512 + ss] = rsqrtf(sq);
          }
        }
    } else {
      // V blocks: transpose through LDS straight into vtg[bh][d][s]
      const int PADT = 136;
      __bf16* Ct = (__bf16*)smem;     // [256 cols][128 rows-of-half + pad]
      int bb = m0 >> 9, s0r = m0 & 511;
#pragma unroll
      for (int hh = 0; hh < 2; ++hh) {
        __builtin_amdgcn_s_barrier();
        if (wm == hh) {
#pragma unroll
          for (int ii = 0; ii < 8; ++ii)
#pragma unroll
            for (int jj = 0; jj < 4; ++jj) {
              bf16x4 pk;
#pragma unroll
              for (int r = 0; r < 4; ++r) pk[r] = (__bf16)acc[ii][jj][r];
              *(bf16x4*)(Ct + (wn * 64 + jj * 16 + l15) * PADT + ii * 16 + quad * 4) = pk;
            }
        }
        __builtin_amdgcn_s_barrier();
#pragma unroll
        for (int p = 0; p < 8; ++p) {
          int c = p * 32 + (tid >> 4);        // local col 0..255 (d within 4 heads)
          int s8 = (tid & 15) * 8;            // s-offset within half
          int h = ((n0 + c) >> 6) & 7, d = c & 63;
          *(bf16x8*)(vtg + ((size_t)(((bb << 3) + h) * 64 + d)) * 512 + s0r + hh * 128 + s8) =
              *(const bf16x8*)(Ct + c * PADT + s8);
        }
      }
      return;
    }
  }

  // normal epilogue: per 128-row half through LDS, wide stores
  const int PADC = 264;
  __bf16* Cs = (__bf16*)smem;
  float bv[4];
  if (EPI == 2) {
#pragma unroll
    for (int j = 0; j < 4; ++j) bv[j] = bias[n0 + wn * 64 + j * 16 + l15];
  }
#pragma unroll
  for (int hh = 0; hh < 2; ++hh) {
    __builtin_amdgcn_s_barrier();
    if (wm == hh) {
#pragma unroll
      for (int i = 0; i < 8; ++i)
#pragma unroll
        for (int j = 0; j < 4; ++j)
#pragma unroll
          for (int r = 0; r < 4; ++r) {
            float v = acc[i][j][r];
            if (EPI == 2) {
              v += bv[j];
              v = v > 0.f ? v : 0.f;
            }
            Cs[(i * 16 + quad * 4 + r) * PADC + wn * 64 + j * 16 + l15] = (__bf16)v;
          }
    }
    __builtin_amdgcn_s_barrier();
#pragma unroll
    for (int p = 0; p < 8; ++p) {
      int rowl = p * 16 + (tid >> 5);
      int c8 = (tid & 31) * 8;
      *(bf16x8*)(Cw + (size_t)(m0 + hh * 128 + rowl) * NDIM + n0 + c8) =
          *(const bf16x8*)(Cs + rowl * PADC + c8);
    }
  }
}

// ---------------------------------------------------------------- attention
__global__ __launch_bounds__(256) void attn_kernel(const __bf16* __restrict__ qkv,
                                                   const __bf16* __restrict__ vtg,
                                                   const float* __restrict__ norms,
                                                   __bf16* __restrict__ out) {
  __shared__ __align__(16) __bf16 Ks[64 * 64];   // [sk][d]
  __shared__ __align__(16) __bf16 Vs[64 * 64];   // [d][sk]
  __shared__ __align__(16) __bf16 P2[4][16 * 72];
  const int tid = threadIdx.x, wave = tid >> 6, lane = tid & 63;
  const int l15 = lane & 15, quad = lane >> 4;
  const int bh = blockIdx.x & 255;
  const int qq = blockIdx.x >> 8;
  const int b = bh >> 3, h = bh & 7;
  const int qbase = qq * 128 + wave * 32;
  const int rs = lane >> 3;
  const int swz_st = ((lane & 7) ^ rs) * 8;
  const int s7 = l15 & 7;

  const __bf16* Qb = qkv + (size_t)(b * 512) * 1536 + h * 64;
  const __bf16* Kb = Qb + 512;
  const __bf16* Vtb = vtg + (size_t)bh * 32768;
  const float* nkinv = norms + 131072 + bh * 512;
  const float* nqinv = norms + bh * 512;
  __bf16* Pw = P2[wave];

  bf16x8 aq[2][2];
  float cq[2];
  for (int ch = 0; ch < 2; ++ch) {
    int qrow = qbase + ch * 16;
    aq[ch][0] = *(const bf16x8*)(Qb + (size_t)(qrow + l15) * 1536 + quad * 8);
    aq[ch][1] = *(const bf16x8*)(Qb + (size_t)(qrow + l15) * 1536 + 32 + quad * 8);
    cq[ch] = nqinv[qrow + l15] * INV_TEMP;
  }

  floatx4 zero = {0.f, 0.f, 0.f, 0.f};
  floatx4 o[2][4];
  float lsum[2] = {0.f, 0.f};
  for (int ch = 0; ch < 2; ++ch)
    for (int jd = 0; jd < 4; ++jd) o[ch][jd] = zero;

  for (int kt = 0; kt < 8; ++kt) {
    int s0 = kt * 64;
    __syncthreads();
    for (int c = 0; c < 4; ++c) {
      int g = wave * 4 + c;
      const __bf16* src;
      __bf16* dst;
      if (g < 8) {
        int sk = g * 8 + rs;
        src = Kb + (size_t)(s0 + sk) * 1536 + swz_st;
        dst = Ks + g * 512;
      } else {
        int g2 = g - 8;
        int d = g2 * 8 + rs;
        src = Vtb + (size_t)d * 512 + s0 + swz_st;
        dst = Vs + g2 * 512;
      }
      gload_lds16(src, dst + lane * 8);
    }
    __syncthreads();

    for (int ch = 0; ch < 2; ++ch) {
      // S^T: 64 sk x 16 q ; lane -> (sk = j*16+quad*4+r, q = l15)
      floatx4 z[4];
      for (int j = 0; j < 4; ++j) {
        int r64 = (j * 16 + l15) * 64;
        bf16x8 k0 = *(const bf16x8*)(Ks + r64 + ((quad ^ s7) * 8));
        bf16x8 k1 = *(const bf16x8*)(Ks + r64 + (((4 + quad) ^ s7) * 8));
        floatx4 zz = zero;
        zz = __builtin_amdgcn_mfma_f32_16x16x32_bf16(k0, aq[ch][0], zz, 0, 0, 0);
        zz = __builtin_amdgcn_mfma_f32_16x16x32_bf16(k1, aq[ch][1], zz, 0, 0, 0);
        z[j] = zz;
      }
      for (int j = 0; j < 4; ++j) {
        floatx4 nk4 = *(const floatx4*)(nkinv + s0 + j * 16 + quad * 4);
        bf16x4 pk;
        for (int r = 0; r < 4; ++r) {
          float p = __expf(z[j][r] * cq[ch] * nk4[r]);
          lsum[ch] += p;
          pk[r] = (__bf16)p;
        }
        *(bf16x4*)(Pw + l15 * 72 + j * 16 + quad * 4) = pk;
      }
      bf16x8 ap0 = *(const bf16x8*)(Pw + l15 * 72 + quad * 8);
      bf16x8 ap1 = *(const bf16x8*)(Pw + l15 * 72 + 32 + quad * 8);
      for (int jd = 0; jd < 4; ++jd) {
        int r64 = (jd * 16 + l15) * 64;
        bf16x8 v0 = *(const bf16x8*)(Vs + r64 + ((quad ^ s7) * 8));
        bf16x8 v1 = *(const bf16x8*)(Vs + r64 + (((4 + quad) ^ s7) * 8));
        o[ch][jd] = __builtin_amdgcn_mfma_f32_16x16x32_bf16(v0, ap0, o[ch][jd], 0, 0, 0);
        o[ch][jd] = __builtin_amdgcn_mfma_f32_16x16x32_bf16(v1, ap1, o[ch][jd], 0, 0, 0);
      }
    }
  }

  for (int ch = 0; ch < 2; ++ch) {
    float s = lsum[ch];
    s += __shfl_xor(s, 16, 64);
    s += __shfl_xor(s, 32, 64);
    float inv = __builtin_amdgcn_rcpf(s);
    int q = qbase + ch * 16 + l15;
    __bf16* op = out + (size_t)(b * 512 + q) * 512 + h * 64;
    for (int jd = 0; jd < 4; ++jd) {
      bf16x4 pk;
      for (int r = 0; r < 4; ++r) pk[r] = (__bf16)(o[ch][jd][r] * inv);
      *(bf16x4*)(op + jd * 16 + quad * 4) = pk;
    }
  }
}

// ---------------------------------------------------------------- residual + layernorm
template <bool X1BF, bool WF, bool WB, bool DUAL>
__global__ __launch_bounds__(256) void resid_ln(const float* __restrict__ X1f,
                                                const __bf16* __restrict__ X1b,
                                                const __bf16* __restrict__ X2,
                                                const __bf16* __restrict__ X2b,
                                                const float* __restrict__ bias,
                                                const float* __restrict__ g,
                                                const float* __restrict__ be,
                                                float* __restrict__ outf,
                                                __bf16* __restrict__ outb) {
  int row = blockIdx.x * 4 + (threadIdx.x >> 6);
  int lane = threadIdx.x & 63;
  float v[8];
  bf16x8 b8 = *(const bf16x8*)(X2 + (size_t)row * 512 + lane * 8);
  if (X1BF) {
    bf16x8 a = *(const bf16x8*)(X1b + (size_t)row * 512 + lane * 8);
    for (int i = 0; i < 8; ++i) v[i] = (float)a[i] + (float)b8[i];
  } else {
    const float4* r1 = (const float4*)(X1f + (size_t)row * 512);
    float4 a0 = r1[lane * 2], a1 = r1[lane * 2 + 1];
    v[0] = a0.x; v[1] = a0.y; v[2] = a0.z; v[3] = a0.w;
    v[4] = a1.x; v[5] = a1.y; v[6] = a1.z; v[7] = a1.w;
    for (int i = 0; i < 8; ++i) v[i] += (float)b8[i];
  }
  if (DUAL) {
    bf16x8 c8 = *(const bf16x8*)(X2b + (size_t)row * 512 + lane * 8);
    for (int i = 0; i < 8; ++i) v[i] += (float)c8[i];
  }
  if (bias) {
    const float* bp = bias + lane * 8;
    for (int i = 0; i < 8; ++i) v[i] += bp[i];
  }
  float s = 0.f, sq = 0.f;
  for (int i = 0; i < 8; ++i) {
    s += v[i];
    sq += v[i] * v[i];
  }
  for (int m = 1; m < 64; m <<= 1) {
    s += __shfl_xor(s, m, 64);
    sq += __shfl_xor(sq, m, 64);
  }
  float mean = s * (1.f / 512.f);
  float var = sq * (1.f / 512.f) - mean * mean;
  float rstd = rsqrtf(var + LN_EPS);
  const float* gp = g + lane * 8;
  const float* bp2 = be + lane * 8;
  float o[8];
  for (int i = 0; i < 8; ++i) o[i] = (v[i] - mean) * rstd * gp[i] + bp2[i];
  if (WF) {
    float4 w0 = {o[0], o[1], o[2], o[3]}, w1 = {o[4], o[5], o[6], o[7]};
    ((float4*)(outf + (size_t)row * 512))[lane * 2] = w0;
    ((float4*)(outf + (size_t)row * 512))[lane * 2 + 1] = w1;
  }
  if (WB) {
    __bf16 tmp[8];
    for (int i = 0; i < 8; ++i) tmp[i] = (__bf16)o[i];
    *(bf16x8*)(outb + (size_t)row * 512 + lane * 8) = *(bf16x8*)tmp;
  }
}

// ---------------------------------------------------------------- launcher
extern "C" void kernel_launch(void* const* d_in, const int* in_sizes, int n_in,
                              void* d_out, int out_size, void* d_ws, size_t ws_size,
                              hipStream_t stream) {
  const float* x     = (const float*)d_in[0];
  const float* w_q   = (const float*)d_in[1];
  const float* w_k   = (const float*)d_in[2];
  const float* w_v   = (const float*)d_in[3];
  const float* w_o   = (const float*)d_in[4];
  const float* w_ff1 = (const float*)d_in[5];
  const float* b_ff1 = (const float*)d_in[6];
  const float* w_ff2 = (const float*)d_in[7];
  const float* b_ff2 = (const float*)d_in[8];
  const float* g1    = (const float*)d_in[9];
  const float* b1    = (const float*)d_in[10];
  const float* g2    = (const float*)d_in[11];
  const float* b2    = (const float*)d_in[12];
  float* out = (float*)d_out;

  char* ws = (char*)d_ws;
  size_t off = 0;
  auto alloc = [&](size_t bytes) -> void* {
    void* p = ws + off;
    off += (bytes + 255) & ~(size_t)255;
    return p;
  };
  __bf16* xb     = (__bf16*)alloc((size_t)Mrows * 512 * 2);
  __bf16* wt_qkv = (__bf16*)alloc((size_t)1536 * 512 * 2);
  __bf16* wt_o   = (__bf16*)alloc((size_t)512 * 512 * 2);
  __bf16* wt_ff1 = (__bf16*)alloc((size_t)2048 * 512 * 2);
  __bf16* wt_ff2 = (__bf16*)alloc((size_t)512 * 2048 * 2);
  __bf16* qkv    = (__bf16*)alloc((size_t)Mrows * 1536 * 2);
  float*  norms  = (float*)alloc((size_t)262144 * 4);
  __bf16* attn   = (__bf16*)alloc((size_t)Mrows * 512 * 2);
  __bf16* projb  = (__bf16*)alloc((size_t)Mrows * 512 * 2);   // contiguous after attn
  __bf16* h1b    = (__bf16*)alloc((size_t)Mrows * 512 * 2);
  __bf16* mid    = (__bf16*)alloc((size_t)Mrows * 2048 * 2);
  __bf16* vtg    = mid;            // alias: vtg dead before w_o writes mid
  __bf16* wo_p   = mid;            // w_o split-K partials: mid + {0, M*512}
  __bf16* f2o    = attn;           // alias: attn dead after w_o GEMM; slice1 -> projb (dead)

  prep_kernel<<<8960, 256, 0, stream>>>(x, xb, w_q, w_k, w_v, w_o, w_ff1, w_ff2,
                                        wt_qkv, wt_qkv + 512 * 512, wt_qkv + 2 * 512 * 512,
                                        wt_o, wt_ff1, wt_ff2);

  // QKV (fused inverse norms + V-transpose into vtg), grid 64x6=384
  gemm256<4, 6, 1536, 512, 1><<<dim3(384), 512, 0, stream>>>(xb, wt_qkv, qkv, nullptr,
                                                             norms, vtg);
  attn_kernel<<<dim3(1024), 256, 0, stream>>>(qkv, vtg, norms, attn);
  // w_o proj -> two bf16 split-K partials into mid (grid 64x2x2=256)
  gemm256<0, 2, 512, 512, 2><<<dim3(256), 512, 0, stream>>>(attn, wt_o, wo_p, nullptr,
                                                            nullptr, nullptr);
  // LN1: x + wo_a + wo_b -> h1b (bf16)
  resid_ln<false, false, true, true><<<4096, 256, 0, stream>>>(x, nullptr, wo_p,
                                                               wo_p + (size_t)Mrows * 512,
                                                               nullptr, g1, b1, nullptr, h1b);
  // FFN1 (+bias, relu): grid 64x8=512
  gemm256<2, 8, 2048, 512, 1><<<dim3(512), 512, 0, stream>>>(h1b, wt_ff1, mid, b_ff1,
                                                             nullptr, nullptr);
  // FFN2 -> two bf16 split-K partials (grid 64x2x2=256)
  gemm256<0, 2, 512, 2048, 2><<<dim3(256), 512, 0, stream>>>(mid, wt_ff2, f2o, nullptr,
                                                             nullptr, nullptr);
  // LN2: h1b + f2o_a + f2o_b + b_ff2 -> out (f32)
  resid_ln<true, true, false, true><<<4096, 256, 0, stream>>>(nullptr, h1b, f2o,
                                                              f2o + (size_t)Mrows * 512,
                                                              b_ff2, g2, b2, out, nullptr);
}

// Round 8
// 321.155 us; speedup vs baseline: 1.0391x; 1.0259x over previous
//
#include <hip/hip_runtime.h>
#include <cmath>

// ---------------------------------------------------------------- types
typedef __bf16 bf16x8 __attribute__((ext_vector_type(8)));
typedef __bf16 bf16x4 __attribute__((ext_vector_type(4)));
typedef float  floatx4 __attribute__((ext_vector_type(4)));

#define LN_EPS 1e-5f
#define INV_TEMP 0.125f   // 1/sqrt(64)

// B=32 S=512 D=512 H=8 DK=DV=64 DFF=2048, M = B*S = 16384
static const int Mrows = 16384;

__device__ __forceinline__ void gload_lds16(const void* g, void* l) {
  __builtin_amdgcn_global_load_lds(
      (const __attribute__((address_space(1))) void*)g,
      (__attribute__((address_space(3))) void*)l, 16, 0, 0);
}

// ---------------------------------------------------------------- fused prep: x->bf16 + 6 weight transposes
__global__ __launch_bounds__(256) void prep_kernel(const float* __restrict__ x, __bf16* __restrict__ xb,
                                                   const float* __restrict__ wq, const float* __restrict__ wk,
                                                   const float* __restrict__ wv, const float* __restrict__ wo,
                                                   const float* __restrict__ wff1, const float* __restrict__ wff2,
                                                   __bf16* __restrict__ tq, __bf16* __restrict__ tk,
                                                   __bf16* __restrict__ tv, __bf16* __restrict__ to_,
                                                   __bf16* __restrict__ tff1, __bf16* __restrict__ tff2) {
  const int bid = blockIdx.x, tid = threadIdx.x;
  if (bid < 8192) {
    int i = bid * 256 + tid;
    float4 v = ((const float4*)x)[i];
    __bf16* d = xb + i * 4;
    d[0] = (__bf16)v.x; d[1] = (__bf16)v.y; d[2] = (__bf16)v.z; d[3] = (__bf16)v.w;
    return;
  }
  __shared__ __bf16 til[64][72];
  int t = bid - 8192;
  const float* src; __bf16* dst; int R, C, bx, by;
  if (t < 256) {
    int w = t >> 6, tt = t & 63;
    const float* srcs[4] = {wq, wk, wv, wo};
    __bf16* dsts[4] = {tq, tk, tv, to_};
    src = srcs[w]; dst = dsts[w]; R = 512; C = 512; bx = tt & 7; by = tt >> 3;
  } else if (t < 512) {
    int tt = t - 256;
    src = wff1; dst = tff1; R = 512; C = 2048; bx = tt & 31; by = tt >> 5;
  } else {
    int tt = t - 512;
    src = wff2; dst = tff2; R = 2048; C = 512; bx = tt & 7; by = tt >> 3;
  }
  const float* s = src + (size_t)(by * 64) * C + bx * 64;
  int r = tid >> 4, c4 = (tid & 15) * 4;
  for (int p = 0; p < 4; ++p) {
    int rr = r + p * 16;
    float4 v = *(const float4*)(s + (size_t)rr * C + c4);
    til[c4 + 0][rr] = (__bf16)v.x;
    til[c4 + 1][rr] = (__bf16)v.y;
    til[c4 + 2][rr] = (__bf16)v.z;
    til[c4 + 3][rr] = (__bf16)v.w;
  }
  __syncthreads();
  __bf16* d = dst + (size_t)(bx * 64) * R + by * 64;
  int orow = tid >> 3, oc8 = (tid & 7) * 8;
  for (int p = 0; p < 2; ++p) {
    int rr = orow + p * 32;
    *(bf16x8*)(d + (size_t)rr * R + oc8) = *(const bf16x8*)(&til[rr][oc8]);
  }
}

// ---------------------------------------------------------------- 128x256 8-wave GEMM, 2-slot K-half ring
// Tile 128x256, 512 threads (waves 2Mx4N, wave owns 64x64 -> acc 4x4 = 64 regs).
// LDS = 2 slots x 24KB (A 128x32 = 8KB + B 256x32 = 16KB) = 48KB -> 2 blocks/CU
// (TLP: second block hides this block's waits, m114). Chunk = 1KB (16 rows x K32),
// pair-line layout (R7-verified, ~0 conflicts): stage lane l -> line l>>3, slot l&7,
// content row = 2*(l>>3)+((l&7)>>2), kseg = ((l&7)&3)^((l>>3)&3);
// read of (row r, kseg q) at byte (r>>1)*128 + ((r&1)*4 + (q^((r>>1)&3)))*16.
// Phase h: vmcnt(0) [own slot-h chunks confirmed; dist ~1 phase, TLP hides] ->
//   barrier [slot h landed block-wide; prev-phase reads retired] ->
//   8 ds_read_b128 -> STAGE slot h+1 (3 gloads) -> lgkmcnt(0) -> 16 MFMA (setprio).
// EPI: 0 plain bf16, 2 bias+relu, 4 QKV (inverse q/k norms + V-transpose).
// NKS>1 = split-K, slice ks writes Cv + ks*M*NDIM.
template <int EPI, int NBN, int NDIM, int KDIM, int NKS>
__global__ __launch_bounds__(512, 4) void gemm256(const __bf16* __restrict__ A,
                                                  const __bf16* __restrict__ Bt,
                                                  __bf16* __restrict__ Cv,
                                                  const float* __restrict__ bias,
                                                  float* __restrict__ norms,
                                                  __bf16* __restrict__ vtg) {
  __shared__ __align__(16) char smem[49152];
  const int tid = threadIdx.x;
  const int wave = tid >> 6, lane = tid & 63;
  const int l15 = lane & 15, quad = lane >> 4;
  const int wm = wave >> 2, wn = wave & 3;

  constexpr int NBM = Mrows / 128;          // 128
  constexpr int NBLK = NBM * NBN * NKS;     // 768 / 512 / 1024 / 512 - all /8
  constexpr int KS = KDIM / NKS;
  constexpr int NTH = KS / 32;

  int id = blockIdx.x;
  int t = (id & 7) * (NBLK >> 3) + (id >> 3);   // XCD-chunked bijective swizzle
  const int ks = t / (NBM * NBN);
  t -= ks * (NBM * NBN);
  const int nblk = t % NBN, mblk = t / NBN;
  const int m0 = mblk * 128, n0 = nblk * 256;
  const __bf16* Ab = A + (size_t)ks * KS;
  const __bf16* Bb = Bt + (size_t)ks * KS;
  __bf16* Cw = Cv + (size_t)ks * Mrows * NDIM;
  (void)bias;

  // ---- stage mapping: 24 chunks (A 0-7, B 8-23), 3 per wave.
  const int l3 = lane >> 3, s_ = lane & 7;
  const int rl = l3 * 2 + (s_ >> 2);            // row within chunk [0,16)
  const int ksw = (s_ & 3) ^ (l3 & 3);          // kseg [0,4)
  const __bf16* sb[3];
  int ldo[3];
#pragma unroll
  for (int j = 0; j < 3; ++j) {
    int c = wave * 3 + j;
    int isB = c >= 8 ? 1 : 0;
    int cc = c - isB * 8;
    int row = cc * 16 + rl;
    sb[j] = (isB ? Bb + (size_t)(n0 + row) * KDIM
                 : Ab + (size_t)(m0 + row) * KDIM) + ksw * 8;
    ldo[j] = isB * 8192 + cc * 1024 + lane * 16;
  }

  // ---- fragment read lane term (bytes) within a 1KB chunk
  const int lrt = (l15 >> 1) * 128 + (((l15 & 1) * 4 + (quad ^ ((l15 >> 1) & 3))) * 16);

  floatx4 zero = {0.f, 0.f, 0.f, 0.f};
  floatx4 acc[4][4];
#pragma unroll
  for (int i = 0; i < 4; ++i)
#pragma unroll
    for (int j = 0; j < 4; ++j) acc[i][j] = zero;

#define STAGEH(h)                                                            \
  {                                                                          \
    _Pragma("unroll") for (int j = 0; j < 3; ++j)                            \
        gload_lds16(sb[j] + (h) * 32, smem + ((h) & 1) * 24576 + ldo[j]);    \
  }

#define PHASE(h, DOSTAGE)                                                    \
  {                                                                          \
    asm volatile("s_waitcnt vmcnt(0)" ::: "memory");                         \
    __builtin_amdgcn_s_barrier();                                            \
    const char* slotp = smem + ((h) & 1) * 24576;                            \
    bf16x8 aF[4], bF[4];                                                     \
    _Pragma("unroll") for (int i = 0; i < 4; ++i)                            \
      aF[i] = *(const bf16x8*)(slotp + (wm * 4 + i) * 1024 + lrt);           \
    _Pragma("unroll") for (int j = 0; j < 4; ++j)                            \
      bF[j] = *(const bf16x8*)(slotp + 8192 + (wn * 4 + j) * 1024 + lrt);    \
    if (DOSTAGE) STAGEH((h) + 1);                                            \
    asm volatile("s_waitcnt lgkmcnt(0)" ::: "memory");                       \
    __builtin_amdgcn_s_setprio(1);                                           \
    _Pragma("unroll") for (int i = 0; i < 4; ++i)                            \
      _Pragma("unroll") for (int j = 0; j < 4; ++j)                          \
        acc[i][j] = __builtin_amdgcn_mfma_f32_16x16x32_bf16(aF[i], bF[j],    \
                                                            acc[i][j], 0, 0, 0); \
    __builtin_amdgcn_s_setprio(0);                                           \
  }

  STAGEH(0);
  for (int h = 0; h < NTH - 1; ++h) PHASE(h, 1);
  PHASE(NTH - 1, 0);

#undef STAGEH
#undef PHASE

  if (EPI == 4) {
    int head_global = (n0 + wn * 64) >> 6;      // wave <-> one head
    int kind = head_global >> 3;                // block-uniform: 0=q 1=k 2=v
    if (kind < 2) {
      // fused INVERSE q/k norms; falls through to the normal C write
      int h = head_global & 7;
#pragma unroll
      for (int ii = 0; ii < 4; ++ii)
#pragma unroll
        for (int r = 0; r < 4; ++r) {
          float sq = 0.f;
#pragma unroll
          for (int jj = 0; jj < 4; ++jj) {
            float v = acc[ii][jj][r];
            sq += v * v;
          }
          for (int m = 1; m < 16; m <<= 1) sq += __shfl_xor(sq, m, 64);
          if (l15 == 0) {
            int arow = m0 + wm * 64 + ii * 16 + quad * 4 + r;
            int bb = arow >> 9, ss = arow & 511;
            norms[kind * 131072 + ((bb << 3) + h) * 512 + ss] = rsqrtf(sq);
          }
        }
    } else {
      // V blocks: transpose through LDS straight into vtg[bh][d][s]
      const int PADT = 72;
      __bf16* Ct = (__bf16*)smem;     // [256 cols][64 s-rows + pad] = 36.9 KB
      int bb = m0 >> 9, s0r = m0 & 511;
#pragma unroll
      for (int hh = 0; hh < 2; ++hh) {           // 64 s-rows per pass
        __builtin_amdgcn_s_barrier();
        if (wm == hh) {
#pragma unroll
          for (int ii = 0; ii < 4; ++ii)
#pragma unroll
            for (int jj = 0; jj < 4; ++jj) {
              bf16x4 pk;
#pragma unroll
              for (int r = 0; r < 4; ++r) pk[r] = (__bf16)acc[ii][jj][r];
              *(bf16x4*)(Ct + (wn * 64 + jj * 16 + l15) * PADT + ii * 16 + quad * 4) = pk;
            }
        }
        __builtin_amdgcn_s_barrier();
#pragma unroll
        for (int p = 0; p < 4; ++p) {
          int c = p * 64 + (tid >> 3);           // local col 0..255 (d in 4 heads)
          int s8 = (tid & 7) * 8;                // s-offset within 64
          int h = ((n0 + c) >> 6) & 7, d = c & 63;
          *(bf16x8*)(vtg + ((size_t)(((bb << 3) + h) * 64 + d)) * 512 + s0r + hh * 64 + s8) =
              *(const bf16x8*)(Ct + c * PADT + s8);
        }
      }
      return;
    }
  }

  // normal epilogue: 64-row halves through LDS, wide stores
  const int PADC = 264;
  __bf16* Cs = (__bf16*)smem;                   // [64][264] = 33.75 KB
  float bv[4];
  if (EPI == 2) {
#pragma unroll
    for (int j = 0; j < 4; ++j) bv[j] = bias[n0 + wn * 64 + j * 16 + l15];
  }
#pragma unroll
  for (int hh = 0; hh < 2; ++hh) {
    __builtin_amdgcn_s_barrier();
    if (wm == hh) {
#pragma unroll
      for (int i = 0; i < 4; ++i)
#pragma unroll
        for (int j = 0; j < 4; ++j)
#pragma unroll
          for (int r = 0; r < 4; ++r) {
            float v = acc[i][j][r];
            if (EPI == 2) {
              v += bv[j];
              v = v > 0.f ? v : 0.f;
            }
            Cs[(i * 16 + quad * 4 + r) * PADC + wn * 64 + j * 16 + l15] = (__bf16)v;
          }
    }
    __builtin_amdgcn_s_barrier();
#pragma unroll
    for (int p = 0; p < 4; ++p) {
      int rowl = p * 16 + (tid >> 5);
      int c8 = (tid & 31) * 8;
      *(bf16x8*)(Cw + (size_t)(m0 + hh * 64 + rowl) * NDIM + n0 + c8) =
          *(const bf16x8*)(Cs + rowl * PADC + c8);
    }
  }
}

// ---------------------------------------------------------------- attention
__global__ __launch_bounds__(256) void attn_kernel(const __bf16* __restrict__ qkv,
                                                   const __bf16* __restrict__ vtg,
                                                   const float* __restrict__ norms,
                                                   __bf16* __restrict__ out) {
  __shared__ __align__(16) __bf16 Ks[64 * 64];   // [sk][d]
  __shared__ __align__(16) __bf16 Vs[64 * 64];   // [d][sk]
  __shared__ __align__(16) __bf16 P2[4][16 * 72];
  const int tid = threadIdx.x, wave = tid >> 6, lane = tid & 63;
  const int l15 = lane & 15, quad = lane >> 4;
  const int bh = blockIdx.x & 255;
  const int qq = blockIdx.x >> 8;
  const int b = bh >> 3, h = bh & 7;
  const int qbase = qq * 128 + wave * 32;
  const int rs = lane >> 3;
  const int swz_st = ((lane & 7) ^ rs) * 8;
  const int s7 = l15 & 7;

  const __bf16* Qb = qkv + (size_t)(b * 512) * 1536 + h * 64;
  const __bf16* Kb = Qb + 512;
  const __bf16* Vtb = vtg + (size_t)bh * 32768;
  const float* nkinv = norms + 131072 + bh * 512;
  const float* nqinv = norms + bh * 512;
  __bf16* Pw = P2[wave];

  bf16x8 aq[2][2];
  float cq[2];
  for (int ch = 0; ch < 2; ++ch) {
    int qrow = qbase + ch * 16;
    aq[ch][0] = *(const bf16x8*)(Qb + (size_t)(qrow + l15) * 1536 + quad * 8);
    aq[ch][1] = *(const bf16x8*)(Qb + (size_t)(qrow + l15) * 1536 + 32 + quad * 8);
    cq[ch] = nqinv[qrow + l15] * INV_TEMP;
  }

  floatx4 zero = {0.f, 0.f, 0.f, 0.f};
  floatx4 o[2][4];
  float lsum[2] = {0.f, 0.f};
  for (int ch = 0; ch < 2; ++ch)
    for (int jd = 0; jd < 4; ++jd) o[ch][jd] = zero;

  for (int kt = 0; kt < 8; ++kt) {
    int s0 = kt * 64;
    __syncthreads();
    for (int c = 0; c < 4; ++c) {
      int g = wave * 4 + c;
      const __bf16* src;
      __bf16* dst;
      if (g < 8) {
        int sk = g * 8 + rs;
        src = Kb + (size_t)(s0 + sk) * 1536 + swz_st;
        dst = Ks + g * 512;
      } else {
        int g2 = g - 8;
        int d = g2 * 8 + rs;
        src = Vtb + (size_t)d * 512 + s0 + swz_st;
        dst = Vs + g2 * 512;
      }
      gload_lds16(src, dst + lane * 8);
    }
    __syncthreads();

    for (int ch = 0; ch < 2; ++ch) {
      // S^T: 64 sk x 16 q ; lane -> (sk = j*16+quad*4+r, q = l15)
      floatx4 z[4];
      for (int j = 0; j < 4; ++j) {
        int r64 = (j * 16 + l15) * 64;
        bf16x8 k0 = *(const bf16x8*)(Ks + r64 + ((quad ^ s7) * 8));
        bf16x8 k1 = *(const bf16x8*)(Ks + r64 + (((4 + quad) ^ s7) * 8));
        floatx4 zz = zero;
        zz = __builtin_amdgcn_mfma_f32_16x16x32_bf16(k0, aq[ch][0], zz, 0, 0, 0);
        zz = __builtin_amdgcn_mfma_f32_16x16x32_bf16(k1, aq[ch][1], zz, 0, 0, 0);
        z[j] = zz;
      }
      for (int j = 0; j < 4; ++j) {
        floatx4 nk4 = *(const floatx4*)(nkinv + s0 + j * 16 + quad * 4);
        bf16x4 pk;
        for (int r = 0; r < 4; ++r) {
          float p = __expf(z[j][r] * cq[ch] * nk4[r]);
          lsum[ch] += p;
          pk[r] = (__bf16)p;
        }
        *(bf16x4*)(Pw + l15 * 72 + j * 16 + quad * 4) = pk;
      }
      bf16x8 ap0 = *(const bf16x8*)(Pw + l15 * 72 + quad * 8);
      bf16x8 ap1 = *(const bf16x8*)(Pw + l15 * 72 + 32 + quad * 8);
      for (int jd = 0; jd < 4; ++jd) {
        int r64 = (jd * 16 + l15) * 64;
        bf16x8 v0 = *(const bf16x8*)(Vs + r64 + ((quad ^ s7) * 8));
        bf16x8 v1 = *(const bf16x8*)(Vs + r64 + (((4 + quad) ^ s7) * 8));
        o[ch][jd] = __builtin_amdgcn_mfma_f32_16x16x32_bf16(v0, ap0, o[ch][jd], 0, 0, 0);
        o[ch][jd] = __builtin_amdgcn_mfma_f32_16x16x32_bf16(v1, ap1, o[ch][jd], 0, 0, 0);
      }
    }
  }

  for (int ch = 0; ch < 2; ++ch) {
    float s = lsum[ch];
    s += __shfl_xor(s, 16, 64);
    s += __shfl_xor(s, 32, 64);
    float inv = __builtin_amdgcn_rcpf(s);
    int q = qbase + ch * 16 + l15;
    __bf16* op = out + (size_t)(b * 512 + q) * 512 + h * 64;
    for (int jd = 0; jd < 4; ++jd) {
      bf16x4 pk;
      for (int r = 0; r < 4; ++r) pk[r] = (__bf16)(o[ch][jd][r] * inv);
      *(bf16x4*)(op + jd * 16 + quad * 4) = pk;
    }
  }
}

// ---------------------------------------------------------------- residual + layernorm
template <bool X1BF, bool WF, bool WB, bool DUAL>
__global__ __launch_bounds__(256) void resid_ln(const float* __restrict__ X1f,
                                                const __bf16* __restrict__ X1b,
                                                const __bf16* __restrict__ X2,
                                                const __bf16* __restrict__ X2b,
                                                const float* __restrict__ bias,
                                                const float* __restrict__ g,
                                                const float* __restrict__ be,
                                                float* __restrict__ outf,
                                                __bf16* __restrict__ outb) {
  int row = blockIdx.x * 4 + (threadIdx.x >> 6);
  int lane = threadIdx.x & 63;
  float v[8];
  bf16x8 b8 = *(const bf16x8*)(X2 + (size_t)row * 512 + lane * 8);
  if (X1BF) {
    bf16x8 a = *(const bf16x8*)(X1b + (size_t)row * 512 + lane * 8);
    for (int i = 0; i < 8; ++i) v[i] = (float)a[i] + (float)b8[i];
  } else {
    const float4* r1 = (const float4*)(X1f + (size_t)row * 512);
    float4 a0 = r1[lane * 2], a1 = r1[lane * 2 + 1];
    v[0] = a0.x; v[1] = a0.y; v[2] = a0.z; v[3] = a0.w;
    v[4] = a1.x; v[5] = a1.y; v[6] = a1.z; v[7] = a1.w;
    for (int i = 0; i < 8; ++i) v[i] += (float)b8[i];
  }
  if (DUAL) {
    bf16x8 c8 = *(const bf16x8*)(X2b + (size_t)row * 512 + lane * 8);
    for (int i = 0; i < 8; ++i) v[i] += (float)c8[i];
  }
  if (bias) {
    const float* bp = bias + lane * 8;
    for (int i = 0; i < 8; ++i) v[i] += bp[i];
  }
  float s = 0.f, sq = 0.f;
  for (int i = 0; i < 8; ++i) {
    s += v[i];
    sq += v[i] * v[i];
  }
  for (int m = 1; m < 64; m <<= 1) {
    s += __shfl_xor(s, m, 64);
    sq += __shfl_xor(sq, m, 64);
  }
  float mean = s * (1.f / 512.f);
  float var = sq * (1.f / 512.f) - mean * mean;
  float rstd = rsqrtf(var + LN_EPS);
  const float* gp = g + lane * 8;
  const float* bp2 = be + lane * 8;
  float o[8];
  for (int i = 0; i < 8; ++i) o[i] = (v[i] - mean) * rstd * gp[i] + bp2[i];
  if (WF) {
    float4 w0 = {o[0], o[1], o[2], o[3]}, w1 = {o[4], o[5], o[6], o[7]};
    ((float4*)(outf + (size_t)row * 512))[lane * 2] = w0;
    ((float4*)(outf + (size_t)row * 512))[lane * 2 + 1] = w1;
  }
  if (WB) {
    __bf16 tmp[8];
    for (int i = 0; i < 8; ++i) tmp[i] = (__bf16)o[i];
    *(bf16x8*)(outb + (size_t)row * 512 + lane * 8) = *(bf16x8*)tmp;
  }
}

// ---------------------------------------------------------------- launcher
extern "C" void kernel_launch(void* const* d_in, const int* in_sizes, int n_in,
                              void* d_out, int out_size, void* d_ws, size_t ws_size,
                              hipStream_t stream) {
  const float* x     = (const float*)d_in[0];
  const float* w_q   = (const float*)d_in[1];
  const float* w_k   = (const float*)d_in[2];
  const float* w_v   = (const float*)d_in[3];
  const float* w_o   = (const float*)d_in[4];
  const float* w_ff1 = (const float*)d_in[5];
  const float* b_ff1 = (const float*)d_in[6];
  const float* w_ff2 = (const float*)d_in[7];
  const float* b_ff2 = (const float*)d_in[8];
  const float* g1    = (const float*)d_in[9];
  const float* b1    = (const float*)d_in[10];
  const float* g2    = (const float*)d_in[11];
  const float* b2    = (const float*)d_in[12];
  float* out = (float*)d_out;

  char* ws = (char*)d_ws;
  size_t off = 0;
  auto alloc = [&](size_t bytes) -> void* {
    void* p = ws + off;
    off += (bytes + 255) & ~(size_t)255;
    return p;
  };
  __bf16* xb     = (__bf16*)alloc((size_t)Mrows * 512 * 2);
  __bf16* wt_qkv = (__bf16*)alloc((size_t)1536 * 512 * 2);
  __bf16* wt_o   = (__bf16*)alloc((size_t)512 * 512 * 2);
  __bf16* wt_ff1 = (__bf16*)alloc((size_t)2048 * 512 * 2);
  __bf16* wt_ff2 = (__bf16*)alloc((size_t)512 * 2048 * 2);
  __bf16* qkv    = (__bf16*)alloc((size_t)Mrows * 1536 * 2);
  float*  norms  = (float*)alloc((size_t)262144 * 4);
  __bf16* attn   = (__bf16*)alloc((size_t)Mrows * 512 * 2);
  __bf16* projb  = (__bf16*)alloc((size_t)Mrows * 512 * 2);   // contiguous after attn
  __bf16* h1b    = (__bf16*)alloc((size_t)Mrows * 512 * 2);
  __bf16* mid    = (__bf16*)alloc((size_t)Mrows * 2048 * 2);
  __bf16* vtg    = mid;            // alias: vtg dead before w_o writes mid
  __bf16* wo_p   = mid;            // w_o split-K partials: mid + {0, M*512}
  __bf16* f2o    = attn;           // alias: attn dead after w_o GEMM; slice1 -> projb (dead)

  prep_kernel<<<8960, 256, 0, stream>>>(x, xb, w_q, w_k, w_v, w_o, w_ff1, w_ff2,
                                        wt_qkv, wt_qkv + 512 * 512, wt_qkv + 2 * 512 * 512,
                                        wt_o, wt_ff1, wt_ff2);

  // QKV (fused inverse norms + V-transpose into vtg), grid 128x6=768
  gemm256<4, 6, 1536, 512, 1><<<dim3(768), 512, 0, stream>>>(xb, wt_qkv, qkv, nullptr,
                                                             norms, vtg);
  attn_kernel<<<dim3(1024), 256, 0, stream>>>(qkv, vtg, norms, attn);
  // w_o proj -> two bf16 split-K partials into mid (grid 128x2x2=512)
  gemm256<0, 2, 512, 512, 2><<<dim3(512), 512, 0, stream>>>(attn, wt_o, wo_p, nullptr,
                                                            nullptr, nullptr);
  // LN1: x + wo_a + wo_b -> h1b (bf16)
  resid_ln<false, false, true, true><<<4096, 256, 0, stream>>>(x, nullptr, wo_p,
                                                               wo_p + (size_t)Mrows * 512,
                                                               nullptr, g1, b1, nullptr, h1b);
  // FFN1 (+bias, relu): grid 128x8=1024
  gemm256<2, 8, 2048, 512, 1><<<dim3(1024), 512, 0, stream>>>(h1b, wt_ff1, mid, b_ff1,
                                                              nullptr, nullptr);
  // FFN2 -> two bf16 split-K partials (grid 128x2x2=512)
  gemm256<0, 2, 512, 2048, 2><<<dim3(512), 512, 0, stream>>>(mid, wt_ff2, f2o, nullptr,
                                                             nullptr, nullptr);
  // LN2: h1b + f2o_a + f2o_b + b_ff2 -> out (f32)
  resid_ln<true, true, false, true><<<4096, 256, 0, stream>>>(nullptr, h1b, f2o,
                                                              f2o + (size_t)Mrows * 512,
                                                              b_ff2, g2, b2, out, nullptr);
}

// Round 9
// 306.134 us; speedup vs baseline: 1.0900x; 1.0491x over previous
//
#include <hip/hip_runtime.h>
#include <cmath>

// ---------------------------------------------------------------- types
typedef __bf16 bf16x8 __attribute__((ext_vector_type(8)));
typedef __bf16 bf16x4 __attribute__((ext_vector_type(4)));
typedef float  floatx4 __attribute__((ext_vector_type(4)));

#define LN_EPS 1e-5f
#define INV_TEMP 0.125f   // 1/sqrt(64)

// B=32 S=512 D=512 H=8 DK=DV=64 DFF=2048, M = B*S = 16384
static const int Mrows = 16384;

__device__ __forceinline__ void gload_lds16(const void* g, void* l) {
  __builtin_amdgcn_global_load_lds(
      (const __attribute__((address_space(1))) void*)g,
      (__attribute__((address_space(3))) void*)l, 16, 0, 0);
}

// ---------------------------------------------------------------- fused prep: x->bf16 + 6 weight transposes
__global__ __launch_bounds__(256) void prep_kernel(const float* __restrict__ x, __bf16* __restrict__ xb,
                                                   const float* __restrict__ wq, const float* __restrict__ wk,
                                                   const float* __restrict__ wv, const float* __restrict__ wo,
                                                   const float* __restrict__ wff1, const float* __restrict__ wff2,
                                                   __bf16* __restrict__ tq, __bf16* __restrict__ tk,
                                                   __bf16* __restrict__ tv, __bf16* __restrict__ to_,
                                                   __bf16* __restrict__ tff1, __bf16* __restrict__ tff2) {
  const int bid = blockIdx.x, tid = threadIdx.x;
  if (bid < 8192) {
    int i = bid * 256 + tid;
    float4 v = ((const float4*)x)[i];
    __bf16* d = xb + i * 4;
    d[0] = (__bf16)v.x; d[1] = (__bf16)v.y; d[2] = (__bf16)v.z; d[3] = (__bf16)v.w;
    return;
  }
  __shared__ __bf16 til[64][72];
  int t = bid - 8192;
  const float* src; __bf16* dst; int R, C, bx, by;
  if (t < 256) {
    int w = t >> 6, tt = t & 63;
    const float* srcs[4] = {wq, wk, wv, wo};
    __bf16* dsts[4] = {tq, tk, tv, to_};
    src = srcs[w]; dst = dsts[w]; R = 512; C = 512; bx = tt & 7; by = tt >> 3;
  } else if (t < 512) {
    int tt = t - 256;
    src = wff1; dst = tff1; R = 512; C = 2048; bx = tt & 31; by = tt >> 5;
  } else {
    int tt = t - 512;
    src = wff2; dst = tff2; R = 2048; C = 512; bx = tt & 7; by = tt >> 3;
  }
  const float* s = src + (size_t)(by * 64) * C + bx * 64;
  int r = tid >> 4, c4 = (tid & 15) * 4;
  for (int p = 0; p < 4; ++p) {
    int rr = r + p * 16;
    float4 v = *(const float4*)(s + (size_t)rr * C + c4);
    til[c4 + 0][rr] = (__bf16)v.x;
    til[c4 + 1][rr] = (__bf16)v.y;
    til[c4 + 2][rr] = (__bf16)v.z;
    til[c4 + 3][rr] = (__bf16)v.w;
  }
  __syncthreads();
  __bf16* d = dst + (size_t)(bx * 64) * R + by * 64;
  int orow = tid >> 3, oc8 = (tid & 7) * 8;
  for (int p = 0; p < 2; ++p) {
    int rr = orow + p * 32;
    *(bf16x8*)(d + (size_t)rr * R + oc8) = *(const bf16x8*)(&til[rr][oc8]);
  }
}

// ---------------------------------------------------------------- 128x256 8-wave GEMM, 3-slot K-half ring
// Tile 128x256, 512 threads (waves 2Mx4N, wave owns 64x64 -> acc 4x4 = 64 regs).
// LDS = 3 slots x 24KB (A 128x32 = 8KB + B 256x32 = 16KB) = 72KB -> 2 blocks/CU
// (TLP hides waits, m114) with DISTANCE-2 prefetch (~2 phases >= L2/HBM latency).
// Chunk = 1KB (16 rows x K32), pair-line layout (R7-verified, ~0 conflicts):
// stage lane l -> line l>>3, slot l&7, content row = 2*(l>>3)+((l&7)>>2),
// kseg = ((l&7)&3)^((l>>3)&3); read of (row r, kseg q) at byte
// (r>>1)*128 + ((r&1)*4 + (q^((r>>1)&3)))*16.
// Phase h (slot sl = h%3): vmcnt(3) [retire slot h's 3 stages, leave slot h+1's
//   3 in flight - never drains] -> barrier [slot h landed block-wide; phase h-1
//   reads retired] -> 8 ds_read_b128 -> STAGE slot h+2 into (sl+2)%3 [= slot
//   read at h-1, WAR-safe past the barrier] -> lgkmcnt(0) -> 16 MFMA (setprio).
// Tail: last phase vmcnt(0).
// EPI: 0 plain bf16, 2 bias+relu, 4 QKV (inverse q/k norms + V-transpose).
// NKS>1 = split-K, slice ks writes Cv + ks*M*NDIM.
template <int EPI, int NBN, int NDIM, int KDIM, int NKS>
__global__ __launch_bounds__(512, 4) void gemm256(const __bf16* __restrict__ A,
                                                  const __bf16* __restrict__ Bt,
                                                  __bf16* __restrict__ Cv,
                                                  const float* __restrict__ bias,
                                                  float* __restrict__ norms,
                                                  __bf16* __restrict__ vtg) {
  __shared__ __align__(16) char smem[73728];
  const int tid = threadIdx.x;
  const int wave = tid >> 6, lane = tid & 63;
  const int l15 = lane & 15, quad = lane >> 4;
  const int wm = wave >> 2, wn = wave & 3;

  constexpr int NBM = Mrows / 128;          // 128
  constexpr int NBLK = NBM * NBN * NKS;     // 768 / 512 / 1024 / 512 - all /8
  constexpr int KS = KDIM / NKS;
  constexpr int NTH = KS / 32;              // >= 8 everywhere

  int id = blockIdx.x;
  int t = (id & 7) * (NBLK >> 3) + (id >> 3);   // XCD-chunked bijective swizzle
  const int ks = t / (NBM * NBN);
  t -= ks * (NBM * NBN);
  const int nblk = t % NBN, mblk = t / NBN;
  const int m0 = mblk * 128, n0 = nblk * 256;
  const __bf16* Ab = A + (size_t)ks * KS;
  const __bf16* Bb = Bt + (size_t)ks * KS;
  __bf16* Cw = Cv + (size_t)ks * Mrows * NDIM;
  (void)bias;

  // ---- stage mapping: 24 chunks (A 0-7, B 8-23), 3 per wave.
  const int l3 = lane >> 3, s_ = lane & 7;
  const int rl = l3 * 2 + (s_ >> 2);            // row within chunk [0,16)
  const int ksw = (s_ & 3) ^ (l3 & 3);          // kseg [0,4)
  const __bf16* sb[3];
  int ldo[3];
#pragma unroll
  for (int j = 0; j < 3; ++j) {
    int c = wave * 3 + j;
    int isB = c >= 8 ? 1 : 0;
    int cc = c - isB * 8;
    int row = cc * 16 + rl;
    sb[j] = (isB ? Bb + (size_t)(n0 + row) * KDIM
                 : Ab + (size_t)(m0 + row) * KDIM) + ksw * 8;
    ldo[j] = isB * 8192 + cc * 1024 + lane * 16;
  }

  // ---- fragment read lane term (bytes) within a 1KB chunk
  const int lrt = (l15 >> 1) * 128 + (((l15 & 1) * 4 + (quad ^ ((l15 >> 1) & 3))) * 16);

  floatx4 zero = {0.f, 0.f, 0.f, 0.f};
  floatx4 acc[4][4];
#pragma unroll
  for (int i = 0; i < 4; ++i)
#pragma unroll
    for (int j = 0; j < 4; ++j) acc[i][j] = zero;

#define STAGEH(h, slotIdx)                                                   \
  {                                                                          \
    _Pragma("unroll") for (int j = 0; j < 3; ++j)                            \
        gload_lds16(sb[j] + (h) * 32, smem + (slotIdx) * 24576 + ldo[j]);    \
  }

#define READMFMA(slotIdx)                                                    \
  {                                                                          \
    const char* slotp = smem + (slotIdx) * 24576;                            \
    bf16x8 aF[4], bF[4];                                                     \
    _Pragma("unroll") for (int i = 0; i < 4; ++i)                            \
      aF[i] = *(const bf16x8*)(slotp + (wm * 4 + i) * 1024 + lrt);           \
    _Pragma("unroll") for (int j = 0; j < 4; ++j)                            \
      bF[j] = *(const bf16x8*)(slotp + 8192 + (wn * 4 + j) * 1024 + lrt);    \
    DOSTAGE_HOOK;                                                            \
    asm volatile("s_waitcnt lgkmcnt(0)" ::: "memory");                       \
    __builtin_amdgcn_s_setprio(1);                                           \
    _Pragma("unroll") for (int i = 0; i < 4; ++i)                            \
      _Pragma("unroll") for (int j = 0; j < 4; ++j)                          \
        acc[i][j] = __builtin_amdgcn_mfma_f32_16x16x32_bf16(aF[i], bF[j],    \
                                                            acc[i][j], 0, 0, 0); \
    __builtin_amdgcn_s_setprio(0);                                           \
  }

  // prologue: stage slots 0,1 (6 loads/thread outstanding)
  STAGEH(0, 0);
  STAGEH(1, 1);

  int sl = 0;
  for (int h = 0; h < NTH - 1; ++h) {
    asm volatile("s_waitcnt vmcnt(3)" ::: "memory");
    __builtin_amdgcn_s_barrier();
    int st = (sl == 0) ? 2 : sl - 1;          // (sl+2)%3
    if (h < NTH - 2) {
#define DOSTAGE_HOOK STAGEH(h + 2, st)
      READMFMA(sl);
#undef DOSTAGE_HOOK
    } else {
#define DOSTAGE_HOOK
      READMFMA(sl);
#undef DOSTAGE_HOOK
    }
    sl = (sl == 2) ? 0 : sl + 1;
  }
  asm volatile("s_waitcnt vmcnt(0)" ::: "memory");
  __builtin_amdgcn_s_barrier();
#define DOSTAGE_HOOK
  READMFMA(sl);
#undef DOSTAGE_HOOK

#undef STAGEH
#undef READMFMA

  if (EPI == 4) {
    int head_global = (n0 + wn * 64) >> 6;      // wave <-> one head
    int kind = head_global >> 3;                // block-uniform: 0=q 1=k 2=v
    if (kind < 2) {
      // fused INVERSE q/k norms; falls through to the normal C write
      int h = head_global & 7;
#pragma unroll
      for (int ii = 0; ii < 4; ++ii)
#pragma unroll
        for (int r = 0; r < 4; ++r) {
          float sq = 0.f;
#pragma unroll
          for (int jj = 0; jj < 4; ++jj) {
            float v = acc[ii][jj][r];
            sq += v * v;
          }
          for (int m = 1; m < 16; m <<= 1) sq += __shfl_xor(sq, m, 64);
          if (l15 == 0) {
            int arow = m0 + wm * 64 + ii * 16 + quad * 4 + r;
            int bb = arow >> 9, ss = arow & 511;
            norms[kind * 131072 + ((bb << 3) + h) * 512 + ss] = rsqrtf(sq);
          }
        }
    } else {
      // V blocks: transpose through LDS straight into vtg[bh][d][s]
      const int PADT = 72;
      __bf16* Ct = (__bf16*)smem;     // [256 cols][64 s-rows + pad] = 36.9 KB
      int bb = m0 >> 9, s0r = m0 & 511;
#pragma unroll
      for (int hh = 0; hh < 2; ++hh) {           // 64 s-rows per pass
        __builtin_amdgcn_s_barrier();
        if (wm == hh) {
#pragma unroll
          for (int ii = 0; ii < 4; ++ii)
#pragma unroll
            for (int jj = 0; jj < 4; ++jj) {
              bf16x4 pk;
#pragma unroll
              for (int r = 0; r < 4; ++r) pk[r] = (__bf16)acc[ii][jj][r];
              *(bf16x4*)(Ct + (wn * 64 + jj * 16 + l15) * PADT + ii * 16 + quad * 4) = pk;
            }
        }
        __builtin_amdgcn_s_barrier();
#pragma unroll
        for (int p = 0; p < 4; ++p) {
          int c = p * 64 + (tid >> 3);           // local col 0..255 (d in 4 heads)
          int s8 = (tid & 7) * 8;                // s-offset within 64
          int h = ((n0 + c) >> 6) & 7, d = c & 63;
          *(bf16x8*)(vtg + ((size_t)(((bb << 3) + h) * 64 + d)) * 512 + s0r + hh * 64 + s8) =
              *(const bf16x8*)(Ct + c * PADT + s8);
        }
      }
      return;
    }
  }

  // normal epilogue: 64-row halves through LDS, wide stores
  const int PADC = 264;
  __bf16* Cs = (__bf16*)smem;                   // [64][264] = 33.75 KB
  float bv[4];
  if (EPI == 2) {
#pragma unroll
    for (int j = 0; j < 4; ++j) bv[j] = bias[n0 + wn * 64 + j * 16 + l15];
  }
#pragma unroll
  for (int hh = 0; hh < 2; ++hh) {
    __builtin_amdgcn_s_barrier();
    if (wm == hh) {
#pragma unroll
      for (int i = 0; i < 4; ++i)
#pragma unroll
        for (int j = 0; j < 4; ++j)
#pragma unroll
          for (int r = 0; r < 4; ++r) {
            float v = acc[i][j][r];
            if (EPI == 2) {
              v += bv[j];
              v = v > 0.f ? v : 0.f;
            }
            Cs[(i * 16 + quad * 4 + r) * PADC + wn * 64 + j * 16 + l15] = (__bf16)v;
          }
    }
    __builtin_amdgcn_s_barrier();
#pragma unroll
    for (int p = 0; p < 4; ++p) {
      int rowl = p * 16 + (tid >> 5);
      int c8 = (tid & 31) * 8;
      *(bf16x8*)(Cw + (size_t)(m0 + hh * 64 + rowl) * NDIM + n0 + c8) =
          *(const bf16x8*)(Cs + rowl * PADC + c8);
    }
  }
}

// ---------------------------------------------------------------- attention
__global__ __launch_bounds__(256) void attn_kernel(const __bf16* __restrict__ qkv,
                                                   const __bf16* __restrict__ vtg,
                                                   const float* __restrict__ norms,
                                                   __bf16* __restrict__ out) {
  __shared__ __align__(16) __bf16 Ks[64 * 64];   // [sk][d]
  __shared__ __align__(16) __bf16 Vs[64 * 64];   // [d][sk]
  __shared__ __align__(16) __bf16 P2[4][16 * 72];
  const int tid = threadIdx.x, wave = tid >> 6, lane = tid & 63;
  const int l15 = lane & 15, quad = lane >> 4;
  const int bh = blockIdx.x & 255;
  const int qq = blockIdx.x >> 8;
  const int b = bh >> 3, h = bh & 7;
  const int qbase = qq * 128 + wave * 32;
  const int rs = lane >> 3;
  const int swz_st = ((lane & 7) ^ rs) * 8;
  const int s7 = l15 & 7;

  const __bf16* Qb = qkv + (size_t)(b * 512) * 1536 + h * 64;
  const __bf16* Kb = Qb + 512;
  const __bf16* Vtb = vtg + (size_t)bh * 32768;
  const float* nkinv = norms + 131072 + bh * 512;
  const float* nqinv = norms + bh * 512;
  __bf16* Pw = P2[wave];

  bf16x8 aq[2][2];
  float cq[2];
  for (int ch = 0; ch < 2; ++ch) {
    int qrow = qbase + ch * 16;
    aq[ch][0] = *(const bf16x8*)(Qb + (size_t)(qrow + l15) * 1536 + quad * 8);
    aq[ch][1] = *(const bf16x8*)(Qb + (size_t)(qrow + l15) * 1536 + 32 + quad * 8);
    cq[ch] = nqinv[qrow + l15] * INV_TEMP;
  }

  floatx4 zero = {0.f, 0.f, 0.f, 0.f};
  floatx4 o[2][4];
  float lsum[2] = {0.f, 0.f};
  for (int ch = 0; ch < 2; ++ch)
    for (int jd = 0; jd < 4; ++jd) o[ch][jd] = zero;

  for (int kt = 0; kt < 8; ++kt) {
    int s0 = kt * 64;
    __syncthreads();
    for (int c = 0; c < 4; ++c) {
      int g = wave * 4 + c;
      const __bf16* src;
      __bf16* dst;
      if (g < 8) {
        int sk = g * 8 + rs;
        src = Kb + (size_t)(s0 + sk) * 1536 + swz_st;
        dst = Ks + g * 512;
      } else {
        int g2 = g - 8;
        int d = g2 * 8 + rs;
        src = Vtb + (size_t)d * 512 + s0 + swz_st;
        dst = Vs + g2 * 512;
      }
      gload_lds16(src, dst + lane * 8);
    }
    __syncthreads();

    for (int ch = 0; ch < 2; ++ch) {
      // S^T: 64 sk x 16 q ; lane -> (sk = j*16+quad*4+r, q = l15)
      floatx4 z[4];
      for (int j = 0; j < 4; ++j) {
        int r64 = (j * 16 + l15) * 64;
        bf16x8 k0 = *(const bf16x8*)(Ks + r64 + ((quad ^ s7) * 8));
        bf16x8 k1 = *(const bf16x8*)(Ks + r64 + (((4 + quad) ^ s7) * 8));
        floatx4 zz = zero;
        zz = __builtin_amdgcn_mfma_f32_16x16x32_bf16(k0, aq[ch][0], zz, 0, 0, 0);
        zz = __builtin_amdgcn_mfma_f32_16x16x32_bf16(k1, aq[ch][1], zz, 0, 0, 0);
        z[j] = zz;
      }
      for (int j = 0; j < 4; ++j) {
        floatx4 nk4 = *(const floatx4*)(nkinv + s0 + j * 16 + quad * 4);
        bf16x4 pk;
        for (int r = 0; r < 4; ++r) {
          float p = __expf(z[j][r] * cq[ch] * nk4[r]);
          lsum[ch] += p;
          pk[r] = (__bf16)p;
        }
        *(bf16x4*)(Pw + l15 * 72 + j * 16 + quad * 4) = pk;
      }
      bf16x8 ap0 = *(const bf16x8*)(Pw + l15 * 72 + quad * 8);
      bf16x8 ap1 = *(const bf16x8*)(Pw + l15 * 72 + 32 + quad * 8);
      for (int jd = 0; jd < 4; ++jd) {
        int r64 = (jd * 16 + l15) * 64;
        bf16x8 v0 = *(const bf16x8*)(Vs + r64 + ((quad ^ s7) * 8));
        bf16x8 v1 = *(const bf16x8*)(Vs + r64 + (((4 + quad) ^ s7) * 8));
        o[ch][jd] = __builtin_amdgcn_mfma_f32_16x16x32_bf16(v0, ap0, o[ch][jd], 0, 0, 0);
        o[ch][jd] = __builtin_amdgcn_mfma_f32_16x16x32_bf16(v1, ap1, o[ch][jd], 0, 0, 0);
      }
    }
  }

  for (int ch = 0; ch < 2; ++ch) {
    float s = lsum[ch];
    s += __shfl_xor(s, 16, 64);
    s += __shfl_xor(s, 32, 64);
    float inv = __builtin_amdgcn_rcpf(s);
    int q = qbase + ch * 16 + l15;
    __bf16* op = out + (size_t)(b * 512 + q) * 512 + h * 64;
    for (int jd = 0; jd < 4; ++jd) {
      bf16x4 pk;
      for (int r = 0; r < 4; ++r) pk[r] = (__bf16)(o[ch][jd][r] * inv);
      *(bf16x4*)(op + jd * 16 + quad * 4) = pk;
    }
  }
}

// ---------------------------------------------------------------- residual + layernorm
template <bool X1BF, bool WF, bool WB, bool DUAL>
__global__ __launch_bounds__(256) void resid_ln(const float* __restrict__ X1f,
                                                const __bf16* __restrict__ X1b,
                                                const __bf16* __restrict__ X2,
                                                const __bf16* __restrict__ X2b,
                                                const float* __restrict__ bias,
                                                const float* __restrict__ g,
                                                const float* __restrict__ be,
                                                float* __restrict__ outf,
                                                __bf16* __restrict__ outb) {
  int row = blockIdx.x * 4 + (threadIdx.x >> 6);
  int lane = threadIdx.x & 63;
  float v[8];
  bf16x8 b8 = *(const bf16x8*)(X2 + (size_t)row * 512 + lane * 8);
  if (X1BF) {
    bf16x8 a = *(const bf16x8*)(X1b + (size_t)row * 512 + lane * 8);
    for (int i = 0; i < 8; ++i) v[i] = (float)a[i] + (float)b8[i];
  } else {
    const float4* r1 = (const float4*)(X1f + (size_t)row * 512);
    float4 a0 = r1[lane * 2], a1 = r1[lane * 2 + 1];
    v[0] = a0.x; v[1] = a0.y; v[2] = a0.z; v[3] = a0.w;
    v[4] = a1.x; v[5] = a1.y; v[6] = a1.z; v[7] = a1.w;
    for (int i = 0; i < 8; ++i) v[i] += (float)b8[i];
  }
  if (DUAL) {
    bf16x8 c8 = *(const bf16x8*)(X2b + (size_t)row * 512 + lane * 8);
    for (int i = 0; i < 8; ++i) v[i] += (float)c8[i];
  }
  if (bias) {
    const float* bp = bias + lane * 8;
    for (int i = 0; i < 8; ++i) v[i] += bp[i];
  }
  float s = 0.f, sq = 0.f;
  for (int i = 0; i < 8; ++i) {
    s += v[i];
    sq += v[i] * v[i];
  }
  for (int m = 1; m < 64; m <<= 1) {
    s += __shfl_xor(s, m, 64);
    sq += __shfl_xor(sq, m, 64);
  }
  float mean = s * (1.f / 512.f);
  float var = sq * (1.f / 512.f) - mean * mean;
  float rstd = rsqrtf(var + LN_EPS);
  const float* gp = g + lane * 8;
  const float* bp2 = be + lane * 8;
  float o[8];
  for (int i = 0; i < 8; ++i) o[i] = (v[i] - mean) * rstd * gp[i] + bp2[i];
  if (WF) {
    float4 w0 = {o[0], o[1], o[2], o[3]}, w1 = {o[4], o[5], o[6], o[7]};
    ((float4*)(outf + (size_t)row * 512))[lane * 2] = w0;
    ((float4*)(outf + (size_t)row * 512))[lane * 2 + 1] = w1;
  }
  if (WB) {
    __bf16 tmp[8];
    for (int i = 0; i < 8; ++i) tmp[i] = (__bf16)o[i];
    *(bf16x8*)(outb + (size_t)row * 512 + lane * 8) = *(bf16x8*)tmp;
  }
}

// ---------------------------------------------------------------- launcher
extern "C" void kernel_launch(void* const* d_in, const int* in_sizes, int n_in,
                              void* d_out, int out_size, void* d_ws, size_t ws_size,
                              hipStream_t stream) {
  const float* x     = (const float*)d_in[0];
  const float* w_q   = (const float*)d_in[1];
  const float* w_k   = (const float*)d_in[2];
  const float* w_v   = (const float*)d_in[3];
  const float* w_o   = (const float*)d_in[4];
  const float* w_ff1 = (const float*)d_in[5];
  const float* b_ff1 = (const float*)d_in[6];
  const float* w_ff2 = (const float*)d_in[7];
  const float* b_ff2 = (const float*)d_in[8];
  const float* g1    = (const float*)d_in[9];
  const float* b1    = (const float*)d_in[10];
  const float* g2    = (const float*)d_in[11];
  const float* b2    = (const float*)d_in[12];
  float* out = (float*)d_out;

  char* ws = (char*)d_ws;
  size_t off = 0;
  auto alloc = [&](size_t bytes) -> void* {
    void* p = ws + off;
    off += (bytes + 255) & ~(size_t)255;
    return p;
  };
  __bf16* xb     = (__bf16*)alloc((size_t)Mrows * 512 * 2);
  __bf16* wt_qkv = (__bf16*)alloc((size_t)1536 * 512 * 2);
  __bf16* wt_o   = (__bf16*)alloc((size_t)512 * 512 * 2);
  __bf16* wt_ff1 = (__bf16*)alloc((size_t)2048 * 512 * 2);
  __bf16* wt_ff2 = (__bf16*)alloc((size_t)512 * 2048 * 2);
  __bf16* qkv    = (__bf16*)alloc((size_t)Mrows * 1536 * 2);
  float*  norms  = (float*)alloc((size_t)262144 * 4);
  __bf16* attn   = (__bf16*)alloc((size_t)Mrows * 512 * 2);
  __bf16* projb  = (__bf16*)alloc((size_t)Mrows * 512 * 2);   // contiguous after attn
  __bf16* h1b    = (__bf16*)alloc((size_t)Mrows * 512 * 2);
  __bf16* mid    = (__bf16*)alloc((size_t)Mrows * 2048 * 2);
  __bf16* vtg    = mid;            // alias: vtg dead before w_o writes mid
  __bf16* wo_p   = mid;            // w_o split-K partials: mid + {0, M*512}
  __bf16* f2o    = attn;           // alias: attn dead after w_o GEMM; slice1 -> projb (dead)

  prep_kernel<<<8960, 256, 0, stream>>>(x, xb, w_q, w_k, w_v, w_o, w_ff1, w_ff2,
                                        wt_qkv, wt_qkv + 512 * 512, wt_qkv + 2 * 512 * 512,
                                        wt_o, wt_ff1, wt_ff2);

  // QKV (fused inverse norms + V-transpose into vtg), grid 128x6=768
  gemm256<4, 6, 1536, 512, 1><<<dim3(768), 512, 0, stream>>>(xb, wt_qkv, qkv, nullptr,
                                                             norms, vtg);
  attn_kernel<<<dim3(1024), 256, 0, stream>>>(qkv, vtg, norms, attn);
  // w_o proj -> two bf16 split-K partials into mid (grid 128x2x2=512)
  gemm256<0, 2, 512, 512, 2><<<dim3(512), 512, 0, stream>>>(attn, wt_o, wo_p, nullptr,
                                                            nullptr, nullptr);
  // LN1: x + wo_a + wo_b -> h1b (bf16)
  resid_ln<false, false, true, true><<<4096, 256, 0, stream>>>(x, nullptr, wo_p,
                                                               wo_p + (size_t)Mrows * 512,
                                                               nullptr, g1, b1, nullptr, h1b);
  // FFN1 (+bias, relu): grid 128x8=1024
  gemm256<2, 8, 2048, 512, 1><<<dim3(1024), 512, 0, stream>>>(h1b, wt_ff1, mid, b_ff1,
                                                              nullptr, nullptr);
  // FFN2 -> two bf16 split-K partials (grid 128x2x2=512)
  gemm256<0, 2, 512, 2048, 2><<<dim3(512), 512, 0, stream>>>(mid, wt_ff2, f2o, nullptr,
                                                             nullptr, nullptr);
  // LN2: h1b + f2o_a + f2o_b + b_ff2 -> out (f32)
  resid_ln<true, true, false, true><<<4096, 256, 0, stream>>>(nullptr, h1b, f2o,
                                                              f2o + (size_t)Mrows * 512,
                                                              b_ff2, g2, b2, out, nullptr);
}

// Round 10
// 300.704 us; speedup vs baseline: 1.1097x; 1.0181x over previous
//
#include <hip/hip_runtime.h>
#include <cmath>

// ---------------------------------------------------------------- types
typedef __bf16 bf16x8 __attribute__((ext_vector_type(8)));
typedef __bf16 bf16x4 __attribute__((ext_vector_type(4)));
typedef float  floatx4 __attribute__((ext_vector_type(4)));

#define LN_EPS 1e-5f
#define INV_TEMP 0.125f   // 1/sqrt(64)

// B=32 S=512 D=512 H=8 DK=DV=64 DFF=2048, M = B*S = 16384
static const int Mrows = 16384;

__device__ __forceinline__ void gload_lds16(const void* g, void* l) {
  __builtin_amdgcn_global_load_lds(
      (const __attribute__((address_space(1))) void*)g,
      (__attribute__((address_space(3))) void*)l, 16, 0, 0);
}

// ---------------------------------------------------------------- fused prep: x->bf16 + 6 weight transposes
__global__ __launch_bounds__(256) void prep_kernel(const float* __restrict__ x, __bf16* __restrict__ xb,
                                                   const float* __restrict__ wq, const float* __restrict__ wk,
                                                   const float* __restrict__ wv, const float* __restrict__ wo,
                                                   const float* __restrict__ wff1, const float* __restrict__ wff2,
                                                   __bf16* __restrict__ tq, __bf16* __restrict__ tk,
                                                   __bf16* __restrict__ tv, __bf16* __restrict__ to_,
                                                   __bf16* __restrict__ tff1, __bf16* __restrict__ tff2) {
  const int bid = blockIdx.x, tid = threadIdx.x;
  if (bid < 8192) {
    int i = bid * 256 + tid;
    float4 v = ((const float4*)x)[i];
    __bf16* d = xb + i * 4;
    d[0] = (__bf16)v.x; d[1] = (__bf16)v.y; d[2] = (__bf16)v.z; d[3] = (__bf16)v.w;
    return;
  }
  __shared__ __bf16 til[64][72];
  int t = bid - 8192;
  const float* src; __bf16* dst; int R, C, bx, by;
  if (t < 256) {
    int w = t >> 6, tt = t & 63;
    const float* srcs[4] = {wq, wk, wv, wo};
    __bf16* dsts[4] = {tq, tk, tv, to_};
    src = srcs[w]; dst = dsts[w]; R = 512; C = 512; bx = tt & 7; by = tt >> 3;
  } else if (t < 512) {
    int tt = t - 256;
    src = wff1; dst = tff1; R = 512; C = 2048; bx = tt & 31; by = tt >> 5;
  } else {
    int tt = t - 512;
    src = wff2; dst = tff2; R = 2048; C = 512; bx = tt & 7; by = tt >> 3;
  }
  const float* s = src + (size_t)(by * 64) * C + bx * 64;
  int r = tid >> 4, c4 = (tid & 15) * 4;
  for (int p = 0; p < 4; ++p) {
    int rr = r + p * 16;
    float4 v = *(const float4*)(s + (size_t)rr * C + c4);
    til[c4 + 0][rr] = (__bf16)v.x;
    til[c4 + 1][rr] = (__bf16)v.y;
    til[c4 + 2][rr] = (__bf16)v.z;
    til[c4 + 3][rr] = (__bf16)v.w;
  }
  __syncthreads();
  __bf16* d = dst + (size_t)(bx * 64) * R + by * 64;
  int orow = tid >> 3, oc8 = (tid & 7) * 8;
  for (int p = 0; p < 2; ++p) {
    int rr = orow + p * 32;
    *(bf16x8*)(d + (size_t)rr * R + oc8) = *(const bf16x8*)(&til[rr][oc8]);
  }
}

// ---------------------------------------------------------------- 128x256 8-wave GEMM, 3-slot K-half ring
// (unchanged from round 9 - passing, 46us FFN1, 0 conflicts, 2 blocks/CU)
template <int EPI, int NBN, int NDIM, int KDIM, int NKS>
__global__ __launch_bounds__(512, 4) void gemm256(const __bf16* __restrict__ A,
                                                  const __bf16* __restrict__ Bt,
                                                  __bf16* __restrict__ Cv,
                                                  const float* __restrict__ bias,
                                                  float* __restrict__ norms,
                                                  __bf16* __restrict__ vtg) {
  __shared__ __align__(16) char smem[73728];
  const int tid = threadIdx.x;
  const int wave = tid >> 6, lane = tid & 63;
  const int l15 = lane & 15, quad = lane >> 4;
  const int wm = wave >> 2, wn = wave & 3;

  constexpr int NBM = Mrows / 128;          // 128
  constexpr int NBLK = NBM * NBN * NKS;
  constexpr int KS = KDIM / NKS;
  constexpr int NTH = KS / 32;

  int id = blockIdx.x;
  int t = (id & 7) * (NBLK >> 3) + (id >> 3);   // XCD-chunked bijective swizzle
  const int ks = t / (NBM * NBN);
  t -= ks * (NBM * NBN);
  const int nblk = t % NBN, mblk = t / NBN;
  const int m0 = mblk * 128, n0 = nblk * 256;
  const __bf16* Ab = A + (size_t)ks * KS;
  const __bf16* Bb = Bt + (size_t)ks * KS;
  __bf16* Cw = Cv + (size_t)ks * Mrows * NDIM;
  (void)bias;

  // stage mapping: 24 chunks (A 0-7, B 8-23), 3 per wave; pair-line layout.
  const int l3 = lane >> 3, s_ = lane & 7;
  const int rl = l3 * 2 + (s_ >> 2);
  const int ksw = (s_ & 3) ^ (l3 & 3);
  const __bf16* sb[3];
  int ldo[3];
#pragma unroll
  for (int j = 0; j < 3; ++j) {
    int c = wave * 3 + j;
    int isB = c >= 8 ? 1 : 0;
    int cc = c - isB * 8;
    int row = cc * 16 + rl;
    sb[j] = (isB ? Bb + (size_t)(n0 + row) * KDIM
                 : Ab + (size_t)(m0 + row) * KDIM) + ksw * 8;
    ldo[j] = isB * 8192 + cc * 1024 + lane * 16;
  }

  const int lrt = (l15 >> 1) * 128 + (((l15 & 1) * 4 + (quad ^ ((l15 >> 1) & 3))) * 16);

  floatx4 zero = {0.f, 0.f, 0.f, 0.f};
  floatx4 acc[4][4];
#pragma unroll
  for (int i = 0; i < 4; ++i)
#pragma unroll
    for (int j = 0; j < 4; ++j) acc[i][j] = zero;

#define STAGEH(h, slotIdx)                                                   \
  {                                                                          \
    _Pragma("unroll") for (int j = 0; j < 3; ++j)                            \
        gload_lds16(sb[j] + (h) * 32, smem + (slotIdx) * 24576 + ldo[j]);    \
  }

#define READMFMA(slotIdx)                                                    \
  {                                                                          \
    const char* slotp = smem + (slotIdx) * 24576;                            \
    bf16x8 aF[4], bF[4];                                                     \
    _Pragma("unroll") for (int i = 0; i < 4; ++i)                            \
      aF[i] = *(const bf16x8*)(slotp + (wm * 4 + i) * 1024 + lrt);           \
    _Pragma("unroll") for (int j = 0; j < 4; ++j)                            \
      bF[j] = *(const bf16x8*)(slotp + 8192 + (wn * 4 + j) * 1024 + lrt);    \
    DOSTAGE_HOOK;                                                            \
    asm volatile("s_waitcnt lgkmcnt(0)" ::: "memory");                       \
    __builtin_amdgcn_s_setprio(1);                                           \
    _Pragma("unroll") for (int i = 0; i < 4; ++i)                            \
      _Pragma("unroll") for (int j = 0; j < 4; ++j)                          \
        acc[i][j] = __builtin_amdgcn_mfma_f32_16x16x32_bf16(aF[i], bF[j],    \
                                                            acc[i][j], 0, 0, 0); \
    __builtin_amdgcn_s_setprio(0);                                           \
  }

  STAGEH(0, 0);
  STAGEH(1, 1);

  int sl = 0;
  for (int h = 0; h < NTH - 1; ++h) {
    asm volatile("s_waitcnt vmcnt(3)" ::: "memory");
    __builtin_amdgcn_s_barrier();
    int st = (sl == 0) ? 2 : sl - 1;          // (sl+2)%3
    if (h < NTH - 2) {
#define DOSTAGE_HOOK STAGEH(h + 2, st)
      READMFMA(sl);
#undef DOSTAGE_HOOK
    } else {
#define DOSTAGE_HOOK
      READMFMA(sl);
#undef DOSTAGE_HOOK
    }
    sl = (sl == 2) ? 0 : sl + 1;
  }
  asm volatile("s_waitcnt vmcnt(0)" ::: "memory");
  __builtin_amdgcn_s_barrier();
#define DOSTAGE_HOOK
  READMFMA(sl);
#undef DOSTAGE_HOOK

#undef STAGEH
#undef READMFMA

  if (EPI == 4) {
    int head_global = (n0 + wn * 64) >> 6;
    int kind = head_global >> 3;
    if (kind < 2) {
      int h = head_global & 7;
#pragma unroll
      for (int ii = 0; ii < 4; ++ii)
#pragma unroll
        for (int r = 0; r < 4; ++r) {
          float sq = 0.f;
#pragma unroll
          for (int jj = 0; jj < 4; ++jj) {
            float v = acc[ii][jj][r];
            sq += v * v;
          }
          for (int m = 1; m < 16; m <<= 1) sq += __shfl_xor(sq, m, 64);
          if (l15 == 0) {
            int arow = m0 + wm * 64 + ii * 16 + quad * 4 + r;
            int bb = arow >> 9, ss = arow & 511;
            norms[kind * 131072 + ((bb << 3) + h) * 512 + ss] = rsqrtf(sq);
          }
        }
    } else {
      const int PADT = 72;
      __bf16* Ct = (__bf16*)smem;
      int bb = m0 >> 9, s0r = m0 & 511;
#pragma unroll
      for (int hh = 0; hh < 2; ++hh) {
        __builtin_amdgcn_s_barrier();
        if (wm == hh) {
#pragma unroll
          for (int ii = 0; ii < 4; ++ii)
#pragma unroll
            for (int jj = 0; jj < 4; ++jj) {
              bf16x4 pk;
#pragma unroll
              for (int r = 0; r < 4; ++r) pk[r] = (__bf16)acc[ii][jj][r];
              *(bf16x4*)(Ct + (wn * 64 + jj * 16 + l15) * PADT + ii * 16 + quad * 4) = pk;
            }
        }
        __builtin_amdgcn_s_barrier();
#pragma unroll
        for (int p = 0; p < 4; ++p) {
          int c = p * 64 + (tid >> 3);
          int s8 = (tid & 7) * 8;
          int h = ((n0 + c) >> 6) & 7, d = c & 63;
          *(bf16x8*)(vtg + ((size_t)(((bb << 3) + h) * 64 + d)) * 512 + s0r + hh * 64 + s8) =
              *(const bf16x8*)(Ct + c * PADT + s8);
        }
      }
      return;
    }
  }

  const int PADC = 264;
  __bf16* Cs = (__bf16*)smem;
  float bv[4];
  if (EPI == 2) {
#pragma unroll
    for (int j = 0; j < 4; ++j) bv[j] = bias[n0 + wn * 64 + j * 16 + l15];
  }
#pragma unroll
  for (int hh = 0; hh < 2; ++hh) {
    __builtin_amdgcn_s_barrier();
    if (wm == hh) {
#pragma unroll
      for (int i = 0; i < 4; ++i)
#pragma unroll
        for (int j = 0; j < 4; ++j)
#pragma unroll
          for (int r = 0; r < 4; ++r) {
            float v = acc[i][j][r];
            if (EPI == 2) {
              v += bv[j];
              v = v > 0.f ? v : 0.f;
            }
            Cs[(i * 16 + quad * 4 + r) * PADC + wn * 64 + j * 16 + l15] = (__bf16)v;
          }
    }
    __builtin_amdgcn_s_barrier();
#pragma unroll
    for (int p = 0; p < 4; ++p) {
      int rowl = p * 16 + (tid >> 5);
      int c8 = (tid & 31) * 8;
      *(bf16x8*)(Cw + (size_t)(m0 + hh * 64 + rowl) * NDIM + n0 + c8) =
          *(const bf16x8*)(Cs + rowl * PADC + c8);
    }
  }
}

// ---------------------------------------------------------------- attention (2-slot K/V ring, hoisted fragments)
// grid 1024: bh = id&255, qq = id>>8. Wave: 32 q-rows (2 chunks of 16).
// Per kt: vmcnt(0)+barrier [slot kt&1 staged; prior reads of other slot retired]
//   -> stage kt+1 into slot^1 (lands under ~2000cy of compute)
//   -> read K frags ONCE (8 b128, shared by both ch) -> 16 MFMA S^T
//   -> read V frags ONCE (8 b128) -> per ch: exp+P2 write (8 b64), ap read (4
//      b128), 16 MFMA PV.  36->20 b128/wave/kt: LDS-pipe floor nearly halved.
__global__ __launch_bounds__(256) void attn_kernel(const __bf16* __restrict__ qkv,
                                                   const __bf16* __restrict__ vtg,
                                                   const float* __restrict__ norms,
                                                   __bf16* __restrict__ out) {
  __shared__ __align__(16) __bf16 KV[2][8192];   // [slot][K 8KB | V 8KB] = 32KB
  __shared__ __align__(16) __bf16 P2[4][16 * 72];
  const int tid = threadIdx.x, wave = tid >> 6, lane = tid & 63;
  const int l15 = lane & 15, quad = lane >> 4;
  const int bh = blockIdx.x & 255;
  const int qq = blockIdx.x >> 8;
  const int b = bh >> 3, h = bh & 7;
  const int qbase = qq * 128 + wave * 32;
  const int rs = lane >> 3;
  const int swz_st = ((lane & 7) ^ rs) * 8;
  const int s7 = l15 & 7;

  const __bf16* Qb = qkv + (size_t)(b * 512) * 1536 + h * 64;
  const __bf16* Kb = Qb + 512;
  const __bf16* Vtb = vtg + (size_t)bh * 32768;
  const float* nkinv = norms + 131072 + bh * 512;
  const float* nqinv = norms + bh * 512;
  __bf16* Pw = P2[wave];

  bf16x8 aq[2][2];
  float cq[2];
  for (int ch = 0; ch < 2; ++ch) {
    int qrow = qbase + ch * 16;
    aq[ch][0] = *(const bf16x8*)(Qb + (size_t)(qrow + l15) * 1536 + quad * 8);
    aq[ch][1] = *(const bf16x8*)(Qb + (size_t)(qrow + l15) * 1536 + 32 + quad * 8);
    cq[ch] = nqinv[qrow + l15] * INV_TEMP;
  }

  floatx4 zero = {0.f, 0.f, 0.f, 0.f};
  floatx4 o[2][4];
  float lsum[2] = {0.f, 0.f};
  for (int ch = 0; ch < 2; ++ch)
    for (int jd = 0; jd < 4; ++jd) o[ch][jd] = zero;

#define STAGEKV(kt, s)                                                        \
  {                                                                           \
    int s0q = (kt) * 64;                                                      \
    _Pragma("unroll") for (int c = 0; c < 4; ++c) {                           \
      int g = wave * 4 + c;                                                   \
      const __bf16* src;                                                      \
      __bf16* dst;                                                            \
      if (g < 8) {                                                            \
        int sk = g * 8 + rs;                                                  \
        src = Kb + (size_t)(s0q + sk) * 1536 + swz_st;                        \
        dst = KV[s] + g * 512;                                                \
      } else {                                                                \
        int g2 = g - 8;                                                       \
        int dd = g2 * 8 + rs;                                                 \
        src = Vtb + (size_t)dd * 512 + s0q + swz_st;                          \
        dst = KV[s] + 4096 + g2 * 512;                                        \
      }                                                                       \
      gload_lds16(src, dst + lane * 8);                                       \
    }                                                                         \
  }

  STAGEKV(0, 0);

  for (int kt = 0; kt < 8; ++kt) {
    int s0 = kt * 64;
    int sl = kt & 1;
    asm volatile("s_waitcnt vmcnt(0)" ::: "memory");
    __builtin_amdgcn_s_barrier();
    if (kt < 7) STAGEKV(kt + 1, sl ^ 1);
    const __bf16* Ks = KV[sl];
    const __bf16* Vs = KV[sl] + 4096;

    // nk once per kt (shared by both ch)
    floatx4 nk[4];
#pragma unroll
    for (int j = 0; j < 4; ++j)
      nk[j] = *(const floatx4*)(nkinv + s0 + j * 16 + quad * 4);

    // K fragments once (8 b128)
    bf16x8 kf[4][2];
#pragma unroll
    for (int j = 0; j < 4; ++j) {
      int r64 = (j * 16 + l15) * 64;
      kf[j][0] = *(const bf16x8*)(Ks + r64 + ((quad ^ s7) * 8));
      kf[j][1] = *(const bf16x8*)(Ks + r64 + (((4 + quad) ^ s7) * 8));
    }

    // S^T both ch: lane -> (sk = j*16+quad*4+r, q = l15)
    floatx4 z[2][4];
    __builtin_amdgcn_s_setprio(1);
#pragma unroll
    for (int ch = 0; ch < 2; ++ch)
#pragma unroll
      for (int j = 0; j < 4; ++j) {
        floatx4 zz = zero;
        zz = __builtin_amdgcn_mfma_f32_16x16x32_bf16(kf[j][0], aq[ch][0], zz, 0, 0, 0);
        zz = __builtin_amdgcn_mfma_f32_16x16x32_bf16(kf[j][1], aq[ch][1], zz, 0, 0, 0);
        z[ch][j] = zz;
      }
    __builtin_amdgcn_s_setprio(0);

    // V fragments once (8 b128)
    bf16x8 vf[4][2];
#pragma unroll
    for (int jd = 0; jd < 4; ++jd) {
      int r64 = (jd * 16 + l15) * 64;
      vf[jd][0] = *(const bf16x8*)(Vs + r64 + ((quad ^ s7) * 8));
      vf[jd][1] = *(const bf16x8*)(Vs + r64 + (((4 + quad) ^ s7) * 8));
    }

#pragma unroll
    for (int ch = 0; ch < 2; ++ch) {
      // softmax numerator + P write (per-wave P2, 8 b64 writes)
#pragma unroll
      for (int j = 0; j < 4; ++j) {
        bf16x4 pk;
#pragma unroll
        for (int r = 0; r < 4; ++r) {
          float p = __expf(z[ch][j][r] * cq[ch] * nk[j][r]);
          lsum[ch] += p;
          pk[r] = (__bf16)p;
        }
        *(bf16x4*)(Pw + l15 * 72 + j * 16 + quad * 4) = pk;
      }
      bf16x8 ap0 = *(const bf16x8*)(Pw + l15 * 72 + quad * 8);
      bf16x8 ap1 = *(const bf16x8*)(Pw + l15 * 72 + 32 + quad * 8);
      __builtin_amdgcn_s_setprio(1);
#pragma unroll
      for (int jd = 0; jd < 4; ++jd) {
        o[ch][jd] = __builtin_amdgcn_mfma_f32_16x16x32_bf16(vf[jd][0], ap0, o[ch][jd], 0, 0, 0);
        o[ch][jd] = __builtin_amdgcn_mfma_f32_16x16x32_bf16(vf[jd][1], ap1, o[ch][jd], 0, 0, 0);
      }
      __builtin_amdgcn_s_setprio(0);
    }
  }
#undef STAGEKV

  for (int ch = 0; ch < 2; ++ch) {
    float s = lsum[ch];
    s += __shfl_xor(s, 16, 64);
    s += __shfl_xor(s, 32, 64);
    float inv = __builtin_amdgcn_rcpf(s);
    int q = qbase + ch * 16 + l15;
    __bf16* op = out + (size_t)(b * 512 + q) * 512 + h * 64;
    for (int jd = 0; jd < 4; ++jd) {
      bf16x4 pk;
      for (int r = 0; r < 4; ++r) pk[r] = (__bf16)(o[ch][jd][r] * inv);
      *(bf16x4*)(op + jd * 16 + quad * 4) = pk;
    }
  }
}

// ---------------------------------------------------------------- residual + layernorm
template <bool X1BF, bool WF, bool WB, bool DUAL>
__global__ __launch_bounds__(256) void resid_ln(const float* __restrict__ X1f,
                                                const __bf16* __restrict__ X1b,
                                                const __bf16* __restrict__ X2,
                                                const __bf16* __restrict__ X2b,
                                                const float* __restrict__ bias,
                                                const float* __restrict__ g,
                                                const float* __restrict__ be,
                                                float* __restrict__ outf,
                                                __bf16* __restrict__ outb) {
  int row = blockIdx.x * 4 + (threadIdx.x >> 6);
  int lane = threadIdx.x & 63;
  float v[8];
  bf16x8 b8 = *(const bf16x8*)(X2 + (size_t)row * 512 + lane * 8);
  if (X1BF) {
    bf16x8 a = *(const bf16x8*)(X1b + (size_t)row * 512 + lane * 8);
    for (int i = 0; i < 8; ++i) v[i] = (float)a[i] + (float)b8[i];
  } else {
    const float4* r1 = (const float4*)(X1f + (size_t)row * 512);
    float4 a0 = r1[lane * 2], a1 = r1[lane * 2 + 1];
    v[0] = a0.x; v[1] = a0.y; v[2] = a0.z; v[3] = a0.w;
    v[4] = a1.x; v[5] = a1.y; v[6] = a1.z; v[7] = a1.w;
    for (int i = 0; i < 8; ++i) v[i] += (float)b8[i];
  }
  if (DUAL) {
    bf16x8 c8 = *(const bf16x8*)(X2b + (size_t)row * 512 + lane * 8);
    for (int i = 0; i < 8; ++i) v[i] += (float)c8[i];
  }
  if (bias) {
    const float* bp = bias + lane * 8;
    for (int i = 0; i < 8; ++i) v[i] += bp[i];
  }
  float s = 0.f, sq = 0.f;
  for (int i = 0; i < 8; ++i) {
    s += v[i];
    sq += v[i] * v[i];
  }
  for (int m = 1; m < 64; m <<= 1) {
    s += __shfl_xor(s, m, 64);
    sq += __shfl_xor(sq, m, 64);
  }
  float mean = s * (1.f / 512.f);
  float var = sq * (1.f / 512.f) - mean * mean;
  float rstd = rsqrtf(var + LN_EPS);
  const float* gp = g + lane * 8;
  const float* bp2 = be + lane * 8;
  float o[8];
  for (int i = 0; i < 8; ++i) o[i] = (v[i] - mean) * rstd * gp[i] + bp2[i];
  if (WF) {
    float4 w0 = {o[0], o[1], o[2], o[3]}, w1 = {o[4], o[5], o[6], o[7]};
    ((float4*)(outf + (size_t)row * 512))[lane * 2] = w0;
    ((float4*)(outf + (size_t)row * 512))[lane * 2 + 1] = w1;
  }
  if (WB) {
    __bf16 tmp[8];
    for (int i = 0; i < 8; ++i) tmp[i] = (__bf16)o[i];
    *(bf16x8*)(outb + (size_t)row * 512 + lane * 8) = *(bf16x8*)tmp;
  }
}

// ---------------------------------------------------------------- launcher
extern "C" void kernel_launch(void* const* d_in, const int* in_sizes, int n_in,
                              void* d_out, int out_size, void* d_ws, size_t ws_size,
                              hipStream_t stream) {
  const float* x     = (const float*)d_in[0];
  const float* w_q   = (const float*)d_in[1];
  const float* w_k   = (const float*)d_in[2];
  const float* w_v   = (const float*)d_in[3];
  const float* w_o   = (const float*)d_in[4];
  const float* w_ff1 = (const float*)d_in[5];
  const float* b_ff1 = (const float*)d_in[6];
  const float* w_ff2 = (const float*)d_in[7];
  const float* b_ff2 = (const float*)d_in[8];
  const float* g1    = (const float*)d_in[9];
  const float* b1    = (const float*)d_in[10];
  const float* g2    = (const float*)d_in[11];
  const float* b2    = (const float*)d_in[12];
  float* out = (float*)d_out;

  char* ws = (char*)d_ws;
  size_t off = 0;
  auto alloc = [&](size_t bytes) -> void* {
    void* p = ws + off;
    off += (bytes + 255) & ~(size_t)255;
    return p;
  };
  __bf16* xb     = (__bf16*)alloc((size_t)Mrows * 512 * 2);
  __bf16* wt_qkv = (__bf16*)alloc((size_t)1536 * 512 * 2);
  __bf16* wt_o   = (__bf16*)alloc((size_t)512 * 512 * 2);
  __bf16* wt_ff1 = (__bf16*)alloc((size_t)2048 * 512 * 2);
  __bf16* wt_ff2 = (__bf16*)alloc((size_t)512 * 2048 * 2);
  __bf16* qkv    = (__bf16*)alloc((size_t)Mrows * 1536 * 2);
  float*  norms  = (float*)alloc((size_t)262144 * 4);
  __bf16* attn   = (__bf16*)alloc((size_t)Mrows * 512 * 2);
  __bf16* projb  = (__bf16*)alloc((size_t)Mrows * 512 * 2);   // contiguous after attn
  __bf16* h1b    = (__bf16*)alloc((size_t)Mrows * 512 * 2);
  __bf16* mid    = (__bf16*)alloc((size_t)Mrows * 2048 * 2);
  __bf16* vtg    = mid;            // alias: vtg dead before w_o writes mid
  __bf16* wo_p   = mid;            // w_o split-K partials: mid + {0, M*512}
  __bf16* f2o    = attn;           // alias: attn dead after w_o GEMM; slice1 -> projb (dead)

  prep_kernel<<<8960, 256, 0, stream>>>(x, xb, w_q, w_k, w_v, w_o, w_ff1, w_ff2,
                                        wt_qkv, wt_qkv + 512 * 512, wt_qkv + 2 * 512 * 512,
                                        wt_o, wt_ff1, wt_ff2);

  // QKV (fused inverse norms + V-transpose into vtg), grid 128x6=768
  gemm256<4, 6, 1536, 512, 1><<<dim3(768), 512, 0, stream>>>(xb, wt_qkv, qkv, nullptr,
                                                             norms, vtg);
  attn_kernel<<<dim3(1024), 256, 0, stream>>>(qkv, vtg, norms, attn);
  // w_o proj -> two bf16 split-K partials into mid (grid 128x2x2=512)
  gemm256<0, 2, 512, 512, 2><<<dim3(512), 512, 0, stream>>>(attn, wt_o, wo_p, nullptr,
                                                            nullptr, nullptr);
  // LN1: x + wo_a + wo_b -> h1b (bf16)
  resid_ln<false, false, true, true><<<4096, 256, 0, stream>>>(x, nullptr, wo_p,
                                                               wo_p + (size_t)Mrows * 512,
                                                               nullptr, g1, b1, nullptr, h1b);
  // FFN1 (+bias, relu): grid 128x8=1024
  gemm256<2, 8, 2048, 512, 1><<<dim3(1024), 512, 0, stream>>>(h1b, wt_ff1, mid, b_ff1,
                                                              nullptr, nullptr);
  // FFN2 -> two bf16 split-K partials (grid 128x2x2=512)
  gemm256<0, 2, 512, 2048, 2><<<dim3(512), 512, 0, stream>>>(mid, wt_ff2, f2o, nullptr,
                                                             nullptr, nullptr);
  // LN2: h1b + f2o_a + f2o_b + b_ff2 -> out (f32)
  resid_ln<true, true, false, true><<<4096, 256, 0, stream>>>(nullptr, h1b, f2o,
                                                              f2o + (size_t)Mrows * 512,
                                                              b_ff2, g2, b2, out, nullptr);
}